// Round 4
// baseline (617.163 us; speedup 1.0000x reference)
//
#include <hip/hip_runtime.h>
#include <hip/hip_bf16.h>
#include <stdint.h>

#define B_   8
#define S_   1024
#define D_   256
#define H_   8
#define DH_  32
#define L_   4
#define V_   100
#define DFF_ 1024
#define M_   (B_*S_)   // 8192

using bf16 = __hip_bfloat16;
typedef __bf16 bf16x8 __attribute__((ext_vector_type(8)));
typedef float  f32x4  __attribute__((ext_vector_type(4)));

static __device__ __forceinline__ float b2f(unsigned short u) {
  union { unsigned int i; float f; } w; w.i = ((unsigned int)u) << 16; return w.f;
}

// ---------------------------------------------------------------------------
// Weight prep: f32 sources -> bf16 transposed [N,K]; fused QKV bias (f32).
// grid (1024, 6, 4), block 256
// ---------------------------------------------------------------------------
__global__ void prep_kernel(const float* __restrict__ Wq, const float* __restrict__ Wk,
                            const float* __restrict__ Wv, const float* __restrict__ Wo,
                            const float* __restrict__ W1, const float* __restrict__ W2,
                            const float* __restrict__ Wc,
                            const float* __restrict__ bq, const float* __restrict__ bk,
                            const float* __restrict__ bv,
                            bf16* __restrict__ WqkvT, bf16* __restrict__ WoT,
                            bf16* __restrict__ W1T, bf16* __restrict__ W2T,
                            bf16* __restrict__ WcT, float* __restrict__ bqkv)
{
  const int seg = blockIdx.y, l = blockIdx.z;
  const int i = blockIdx.x * 256 + threadIdx.x;
  if (seg == 0) {                       // WqkvT [l][768][256]
    if (i >= 768*256) return;
    const int n = i >> 8, k = i & 255;
    const float* src = (n < 256) ? Wq : (n < 512) ? Wk : Wv;
    WqkvT[(size_t)l*768*256 + i] = (bf16)src[(size_t)l*65536 + k*256 + (n & 255)];
  } else if (seg == 1) {                // WoT [l][256][256]
    if (i >= 65536) return;
    const int n = i >> 8, k = i & 255;
    WoT[(size_t)l*65536 + i] = (bf16)Wo[(size_t)l*65536 + k*256 + n];
  } else if (seg == 2) {                // W1T [l][1024][256]  (W1 is [256][1024])
    if (i >= 262144) return;
    const int n = i >> 8, k = i & 255;
    W1T[(size_t)l*262144 + i] = (bf16)W1[(size_t)l*262144 + k*1024 + n];
  } else if (seg == 3) {                // W2T [l][256][1024]  (W2 is [1024][256])
    if (i >= 262144) return;
    const int n = i >> 10, k = i & 1023;
    W2T[(size_t)l*262144 + i] = (bf16)W2[(size_t)l*262144 + k*256 + n];
  } else if (seg == 4) {                // WcT [128 pad][256]  (Wc is [256][100])
    if (l != 0 || i >= 128*256) return;
    const int n = i >> 8, k = i & 255;
    WcT[i] = (n < V_) ? (bf16)Wc[k*V_ + n] : (bf16)0.0f;
  } else {                              // fused qkv bias [4][768] f32
    if (l != 0 || i >= L_*768) return;
    const int l2 = i / 768, j = i % 768;
    const float* src = (j < 256) ? bq : (j < 512) ? bk : bv;
    bqkv[i] = src[l2*256 + (j & 255)];
  }
}

// ---------------------------------------------------------------------------
// Embedding (f32) + sinusoidal positions -> bf16 x. grid 8192, block 256
// ---------------------------------------------------------------------------
__global__ void embed_kernel(const int* __restrict__ ids, const float* __restrict__ emb,
                             bf16* __restrict__ x)
{
  const int bs = blockIdx.x;            // 0..8191
  const int d  = threadIdx.x;           // 0..255
  const int s  = bs & (S_-1);
  const int id = ids[bs];
  const int f  = (d < 128) ? (2*d) : (2*(d-128)+1);
  const float inv = powf(10000.f, -(float)f * (1.f/256.f));
  const float pe  = sinf((float)s * inv);
  x[(size_t)bs*D_ + d] = (bf16)(emb[(size_t)id*D_ + d] + pe);
}

// ---------------------------------------------------------------------------
// GEMM: C[M,N] = A[M,K] @ BT[N,K]^T + bias.  128x64 tile, BK=32, 4 waves.
// ---------------------------------------------------------------------------
template<bool RELU, bool OUT_BF16, bool NMASK>
__global__ __launch_bounds__(256) void gemm_bt(
    const bf16* __restrict__ A, const bf16* __restrict__ BT,
    const float* __restrict__ bias, void* __restrict__ C,
    int M, int N, int K)
{
  __shared__ bf16 As[128*32];   // 8 KB
  __shared__ bf16 Bs[64*32];    // 4 KB
  const int tid  = threadIdx.x;
  const int lane = tid & 63, wave = tid >> 6;
  const int quad = lane >> 4, l15 = lane & 15;
  const int m0 = blockIdx.x * 128;
  const int n0 = blockIdx.y * 64;
  const int wm = (wave & 1) * 64;
  const int wn = (wave >> 1) * 32;

  const bf16* a0 = A  + (size_t)m0 * K;
  const bf16* b0 = BT + (size_t)n0 * K;
  const int row = tid >> 2;                 // 0..63
  const int ch  = (tid & 3) * 8;            // k element offset (16B chunks)

  f32x4 acc[4][2] = {};

  for (int k0 = 0; k0 < K; k0 += 32) {
    const bf16x8 av0 = *(const bf16x8*)(a0 + (size_t)row*K      + k0 + ch);
    const bf16x8 av1 = *(const bf16x8*)(a0 + (size_t)(row+64)*K + k0 + ch);
    const bf16x8 bv  = *(const bf16x8*)(b0 + (size_t)row*K      + k0 + ch);
    __syncthreads();
    *(bf16x8*)(As + row*32 + ch)      = av0;
    *(bf16x8*)(As + (row+64)*32 + ch) = av1;
    *(bf16x8*)(Bs + row*32 + ch)      = bv;
    __syncthreads();
    bf16x8 af[4], bfr[2];
    #pragma unroll
    for (int mt = 0; mt < 4; ++mt)
      af[mt] = *(const bf16x8*)(As + (wm + mt*16 + l15)*32 + quad*8);
    #pragma unroll
    for (int nt = 0; nt < 2; ++nt)
      bfr[nt] = *(const bf16x8*)(Bs + (wn + nt*16 + l15)*32 + quad*8);
    #pragma unroll
    for (int mt = 0; mt < 4; ++mt)
      #pragma unroll
      for (int nt = 0; nt < 2; ++nt)
        acc[mt][nt] = __builtin_amdgcn_mfma_f32_16x16x32_bf16(af[mt], bfr[nt], acc[mt][nt], 0, 0, 0);
  }

  #pragma unroll
  for (int nt = 0; nt < 2; ++nt) {
    const int n = n0 + wn + nt*16 + l15;
    if (NMASK && n >= N) continue;
    const float bvs = bias[n];
    #pragma unroll
    for (int mt = 0; mt < 4; ++mt) {
      const int mr = m0 + wm + mt*16 + quad*4;
      #pragma unroll
      for (int r = 0; r < 4; ++r) {
        float v = acc[mt][nt][r] + bvs;
        if (RELU) v = fmaxf(v, 0.f);
        if (OUT_BF16) ((bf16*)C)[(size_t)(mr + r)*N + n] = (bf16)v;
        else          ((float*)C)[(size_t)(mr + r)*N + n] = v;
      }
    }
  }
}

// ---------------------------------------------------------------------------
// V transpose: qkv[.., 512 + h*32 + d] -> vt[b][h][d][s].  grid (16,8,8)
// ---------------------------------------------------------------------------
__global__ void transv_kernel(const bf16* __restrict__ qkv, bf16* __restrict__ vt)
{
  __shared__ bf16 t[64][33];
  const int s0 = blockIdx.x * 64, h = blockIdx.y, b = blockIdx.z;
  const int tid = threadIdx.x;
  const int dl = tid & 31, sl = tid >> 5;
  #pragma unroll
  for (int i = 0; i < 8; ++i) {
    const int s = sl + i*8;
    t[s][dl] = qkv[((size_t)b*S_ + s0 + s)*768 + 512 + h*DH_ + dl];
  }
  __syncthreads();
  const int ss = tid & 63, dd = tid >> 6;
  #pragma unroll
  for (int i = 0; i < 8; ++i) {
    const int d = dd + i*4;
    vt[(((size_t)b*H_ + h)*DH_ + d)*S_ + s0 + ss] = t[ss][d];
  }
}

// ---------------------------------------------------------------------------
// Flash attention, causal. grid (S/64, H, B), block 256 (4 waves x 16 q-rows)
// ---------------------------------------------------------------------------
__global__ __launch_bounds__(256) void attn_kernel(
    const bf16* __restrict__ qkv, const bf16* __restrict__ vt,
    const int* __restrict__ tsl, bf16* __restrict__ out)
{
  const int qblk = blockIdx.x, h = blockIdx.y, b = blockIdx.z;
  const int lane = threadIdx.x & 63, wave = threadIdx.x >> 6;
  const int quad = lane >> 4, l15 = lane & 15;
  const int q0 = qblk*64 + wave*16;
  const int len = tsl[b];

  __shared__ bf16 Pl[4][16*64];   // per-wave P strip

  const bf16* qb = qkv + (size_t)b*S_*768;
  const bf16* kb = qb + 256 + h*DH_;
  const bf16* vb = vt + ((size_t)b*H_ + h)*DH_*S_;

  const bf16x8 qf = *(const bf16x8*)(qb + (size_t)(q0 + l15)*768 + h*DH_ + quad*8);

  const float NEG = -1e30f;
  float m_run[4], l_run[4], al[4];
  f32x4 o0 = {0.f,0.f,0.f,0.f}, o1 = {0.f,0.f,0.f,0.f};
  #pragma unroll
  for (int r = 0; r < 4; ++r) { m_run[r] = NEG; l_run[r] = 0.f; }

  const float scale = 0.17677669529663687f;  // 1/sqrt(32)
  const int nk = qblk + 1;
  for (int ks = 0; ks < nk; ++ks) {
    const int k0 = ks*64;
    f32x4 s[4];
    #pragma unroll
    for (int nt = 0; nt < 4; ++nt) {
      const bf16x8 kf = *(const bf16x8*)(kb + (size_t)(k0 + nt*16 + l15)*768 + quad*8);
      const f32x4 z = {0.f,0.f,0.f,0.f};
      s[nt] = __builtin_amdgcn_mfma_f32_16x16x32_bf16(qf, kf, z, 0, 0, 0);
    }
    float mx[4];
    #pragma unroll
    for (int r = 0; r < 4; ++r) mx[r] = NEG;
    const int qrow0 = q0 + quad*4;
    #pragma unroll
    for (int nt = 0; nt < 4; ++nt) {
      const int kpos = k0 + nt*16 + l15;
      #pragma unroll
      for (int r = 0; r < 4; ++r) {
        const int qr = qrow0 + r;
        const bool ok = (kpos <= qr) && (kpos < len) && (qr < len);
        const float v = ok ? s[nt][r] * scale : NEG;
        s[nt][r] = v;
        mx[r] = fmaxf(mx[r], v);
      }
    }
    #pragma unroll
    for (int r = 0; r < 4; ++r) {
      float v = mx[r];
      v = fmaxf(v, __shfl_xor(v, 1));
      v = fmaxf(v, __shfl_xor(v, 2));
      v = fmaxf(v, __shfl_xor(v, 4));
      v = fmaxf(v, __shfl_xor(v, 8));
      const float mn = fmaxf(m_run[r], v);
      al[r] = (m_run[r] > -1e29f) ? __expf(m_run[r] - mn) : 0.f;
      m_run[r] = mn;
    }
    float ls[4] = {0.f,0.f,0.f,0.f};
    #pragma unroll
    for (int nt = 0; nt < 4; ++nt)
      #pragma unroll
      for (int r = 0; r < 4; ++r) {
        const float vv = s[nt][r];
        const float p = (vv > -1e29f && m_run[r] > -1e29f) ? __expf(vv - m_run[r]) : 0.f;
        s[nt][r] = p;
        ls[r] += p;
      }
    #pragma unroll
    for (int r = 0; r < 4; ++r) {
      float v = ls[r];
      v += __shfl_xor(v, 1);
      v += __shfl_xor(v, 2);
      v += __shfl_xor(v, 4);
      v += __shfl_xor(v, 8);
      l_run[r] = l_run[r]*al[r] + v;
      o0[r] *= al[r];
      o1[r] *= al[r];
    }
    bf16* pw = &Pl[wave][0];
    #pragma unroll
    for (int nt = 0; nt < 4; ++nt)
      #pragma unroll
      for (int r = 0; r < 4; ++r)
        pw[(quad*4+r)*64 + nt*16 + l15] = (bf16)s[nt][r];
    __syncthreads();
    #pragma unroll
    for (int kc = 0; kc < 2; ++kc) {
      const bf16x8 pf = *(const bf16x8*)(pw + l15*64 + kc*32 + quad*8);
      const bf16x8 vf0 = *(const bf16x8*)(vb + (size_t)l15*S_ + k0 + kc*32 + quad*8);
      o0 = __builtin_amdgcn_mfma_f32_16x16x32_bf16(pf, vf0, o0, 0, 0, 0);
      const bf16x8 vf1 = *(const bf16x8*)(vb + (size_t)(16 + l15)*S_ + k0 + kc*32 + quad*8);
      o1 = __builtin_amdgcn_mfma_f32_16x16x32_bf16(pf, vf1, o1, 0, 0, 0);
    }
    __syncthreads();
  }
  bf16* ob = out + (size_t)b*S_*D_ + h*DH_;
  #pragma unroll
  for (int r = 0; r < 4; ++r) {
    const float inv = 1.f / fmaxf(l_run[r], 1e-30f);
    const size_t rowoff = (size_t)(q0 + quad*4 + r)*D_;
    ob[rowoff + l15]      = (bf16)(o0[r]*inv);
    ob[rowoff + 16 + l15] = (bf16)(o1[r]*inv);
  }
}

// ---------------------------------------------------------------------------
// x = LN(x + y)*g + be.  one wave per 256-wide row; block = 4 rows.
// x/xo may alias. g/be are f32.
// ---------------------------------------------------------------------------
__global__ void addln_kernel(const bf16* x, const float* y,
                             const float* g, const float* be, bf16* xo)
{
  const int row  = blockIdx.x*4 + (threadIdx.x >> 6);
  const int lane = threadIdx.x & 63;
  const bf16*  xr = x + (size_t)row*D_ + lane*4;
  const float* yr = y + (size_t)row*D_ + lane*4;
  const ushort4 xs = *(const ushort4*)xr;
  const float4  yv = *(const float4*)yr;
  const float v0 = b2f(xs.x) + yv.x;
  const float v1 = b2f(xs.y) + yv.y;
  const float v2 = b2f(xs.z) + yv.z;
  const float v3 = b2f(xs.w) + yv.w;
  float sm = v0+v1+v2+v3;
  #pragma unroll
  for (int off = 1; off < 64; off <<= 1) sm += __shfl_xor(sm, off);
  const float mean = sm * (1.f/256.f);
  const float d0 = v0-mean, d1 = v1-mean, d2 = v2-mean, d3 = v3-mean;
  float qs = d0*d0 + d1*d1 + d2*d2 + d3*d3;
  #pragma unroll
  for (int off = 1; off < 64; off <<= 1) qs += __shfl_xor(qs, off);
  const float inv = rsqrtf(qs*(1.f/256.f) + 1e-5f);
  const float4 gv = *(const float4*)(g + lane*4);
  const float4 bv = *(const float4*)(be + lane*4);
  bf16 o0 = (bf16)(d0*inv*gv.x + bv.x);
  bf16 o1 = (bf16)(d1*inv*gv.y + bv.y);
  bf16 o2 = (bf16)(d2*inv*gv.z + bv.z);
  bf16 o3 = (bf16)(d3*inv*gv.w + bv.w);
  ushort4 ov = { *(unsigned short*)&o0, *(unsigned short*)&o1,
                 *(unsigned short*)&o2, *(unsigned short*)&o3 };
  *(ushort4*)(xo + (size_t)row*D_ + lane*4) = ov;
}

// ---------------------------------------------------------------------------
extern "C" void kernel_launch(void* const* d_in, const int* in_sizes, int n_in,
                              void* d_out, int out_size, void* d_ws, size_t ws_size,
                              hipStream_t stream)
{
  const int*   ids = (const int*)d_in[0];
  const int*   tsl = (const int*)d_in[1];
  const float* emb = (const float*)d_in[2];
  const float* Wq  = (const float*)d_in[3];
  const float* bq  = (const float*)d_in[4];
  const float* Wk  = (const float*)d_in[5];
  const float* bk  = (const float*)d_in[6];
  const float* Wv  = (const float*)d_in[7];
  const float* bv  = (const float*)d_in[8];
  const float* Wo  = (const float*)d_in[9];
  const float* bo  = (const float*)d_in[10];
  const float* W1  = (const float*)d_in[11];
  const float* b1  = (const float*)d_in[12];
  const float* W2  = (const float*)d_in[13];
  const float* b2  = (const float*)d_in[14];
  const float* g1  = (const float*)d_in[15];
  const float* be1 = (const float*)d_in[16];
  const float* g2  = (const float*)d_in[17];
  const float* be2 = (const float*)d_in[18];
  const float* Wc  = (const float*)d_in[19];
  const float* bc  = (const float*)d_in[20];

  if (ws_size < (size_t)40*1024*1024) return;   // trips -> absmax 1.65625

  char* p = (char*)d_ws;
  auto carve = [&](size_t bytes) { void* r = (void*)p; p += (bytes + 255) & ~(size_t)255; return r; };
  bf16*  x     = (bf16*) carve((size_t)M_*D_*2);      // 4 MB
  void*  big   =         carve((size_t)M_*DFF_*2);    // 16 MB: qkv | ff1
  bf16*  attn  = (bf16*) carve((size_t)M_*D_*2);      // 4 MB
  void*  vty   =         carve((size_t)M_*D_*4);      // 8 MB: vt | yf
  bf16*  WqkvT = (bf16*) carve((size_t)L_*768*256*2);
  bf16*  WoT   = (bf16*) carve((size_t)L_*65536*2);
  bf16*  W1T   = (bf16*) carve((size_t)L_*262144*2);
  bf16*  W2T   = (bf16*) carve((size_t)L_*262144*2);
  bf16*  WcT   = (bf16*) carve((size_t)128*256*2);
  float* bqkv  = (float*)carve((size_t)L_*768*4);

  bf16*  qkv = (bf16*)big;   // [8192][768], dead after attn
  bf16*  ff1 = (bf16*)big;   // [8192][1024], FF1 gemm -> FF2 gemm
  bf16*  vt  = (bf16*)vty;   // [8][8][32][1024], transv -> attn
  float* yf  = (float*)vty;  // [8192][256] f32, WO/FF2 gemm -> addln (disjoint)

  prep_kernel<<<dim3(1024,6,4), 256, 0, stream>>>(Wq,Wk,Wv,Wo,W1,W2,Wc,bq,bk,bv,
                                                  WqkvT,WoT,W1T,W2T,WcT,bqkv);
  embed_kernel<<<dim3(M_), 256, 0, stream>>>(ids, emb, x);

  for (int l = 0; l < L_; ++l) {
    gemm_bt<false,true,false><<<dim3(64,12), 256, 0, stream>>>(
        x, WqkvT + (size_t)l*768*256, bqkv + l*768, qkv, M_, 768, 256);
    transv_kernel<<<dim3(16,8,8), 256, 0, stream>>>(qkv, vt);
    attn_kernel<<<dim3(16,8,8), 256, 0, stream>>>(qkv, vt, tsl, attn);
    gemm_bt<false,false,false><<<dim3(64,4), 256, 0, stream>>>(
        attn, WoT + (size_t)l*65536, bo + l*256, yf, M_, 256, 256);
    addln_kernel<<<dim3(2048), 256, 0, stream>>>(x, yf, g1 + l*256, be1 + l*256, x);
    gemm_bt<true,true,false><<<dim3(64,16), 256, 0, stream>>>(
        x, W1T + (size_t)l*262144, b1 + l*1024, ff1, M_, 1024, 256);
    gemm_bt<false,false,false><<<dim3(64,4), 256, 0, stream>>>(
        ff1, W2T + (size_t)l*262144, b2 + l*256, yf, M_, 256, 1024);
    addln_kernel<<<dim3(2048), 256, 0, stream>>>(x, yf, g2 + l*256, be2 + l*256, x);
  }

  gemm_bt<false,false,true><<<dim3(64,2), 256, 0, stream>>>(
      x, WcT, bc, (float*)d_out, M_, V_, 256);
}

// Round 5
// 520.472 us; speedup vs baseline: 1.1858x; 1.1858x over previous
//
#include <hip/hip_runtime.h>
#include <hip/hip_bf16.h>
#include <stdint.h>

#define B_   8
#define S_   1024
#define D_   256
#define H_   8
#define DH_  32
#define L_   4
#define V_   100
#define DFF_ 1024
#define M_   (B_*S_)   // 8192

using bf16 = __hip_bfloat16;
typedef __bf16 bf16x8 __attribute__((ext_vector_type(8)));
typedef float  f32x4  __attribute__((ext_vector_type(4)));

static __device__ __forceinline__ float b2f(unsigned short u) {
  union { unsigned int i; float f; } w; w.i = ((unsigned int)u) << 16; return w.f;
}

// async global->LDS DMA: 16B/lane, LDS dest = wave-uniform base + lane*16
static __device__ __forceinline__ void load_lds16(const void* g, void* l) {
  __builtin_amdgcn_global_load_lds((const __attribute__((address_space(1))) void*)g,
                                   (__attribute__((address_space(3))) void*)l,
                                   16, 0, 0);
}

// ---------------------------------------------------------------------------
// Weight prep: f32 sources -> bf16 transposed [N,K]; fused QKV bias (f32).
// ---------------------------------------------------------------------------
__global__ void prep_kernel(const float* __restrict__ Wq, const float* __restrict__ Wk,
                            const float* __restrict__ Wv, const float* __restrict__ Wo,
                            const float* __restrict__ W1, const float* __restrict__ W2,
                            const float* __restrict__ Wc,
                            const float* __restrict__ bq, const float* __restrict__ bk,
                            const float* __restrict__ bv,
                            bf16* __restrict__ WqkvT, bf16* __restrict__ WoT,
                            bf16* __restrict__ W1T, bf16* __restrict__ W2T,
                            bf16* __restrict__ WcT, float* __restrict__ bqkv)
{
  const int seg = blockIdx.y, l = blockIdx.z;
  const int i = blockIdx.x * 256 + threadIdx.x;
  if (seg == 0) {                       // WqkvT [l][768][256]
    if (i >= 768*256) return;
    const int n = i >> 8, k = i & 255;
    const float* src = (n < 256) ? Wq : (n < 512) ? Wk : Wv;
    WqkvT[(size_t)l*768*256 + i] = (bf16)src[(size_t)l*65536 + k*256 + (n & 255)];
  } else if (seg == 1) {                // WoT [l][256][256]
    if (i >= 65536) return;
    const int n = i >> 8, k = i & 255;
    WoT[(size_t)l*65536 + i] = (bf16)Wo[(size_t)l*65536 + k*256 + n];
  } else if (seg == 2) {                // W1T [l][1024][256]
    if (i >= 262144) return;
    const int n = i >> 8, k = i & 255;
    W1T[(size_t)l*262144 + i] = (bf16)W1[(size_t)l*262144 + k*1024 + n];
  } else if (seg == 3) {                // W2T [l][256][1024]
    if (i >= 262144) return;
    const int n = i >> 10, k = i & 1023;
    W2T[(size_t)l*262144 + i] = (bf16)W2[(size_t)l*262144 + k*256 + n];
  } else if (seg == 4) {                // WcT [128 pad][256]
    if (l != 0 || i >= 128*256) return;
    const int n = i >> 8, k = i & 255;
    WcT[i] = (n < V_) ? (bf16)Wc[k*V_ + n] : (bf16)0.0f;
  } else {                              // fused qkv bias [4][768] f32
    if (l != 0 || i >= L_*768) return;
    const int l2 = i / 768, j = i % 768;
    const float* src = (j < 256) ? bq : (j < 512) ? bk : bv;
    bqkv[i] = src[l2*256 + (j & 255)];
  }
}

// ---------------------------------------------------------------------------
__global__ void embed_kernel(const int* __restrict__ ids, const float* __restrict__ emb,
                             bf16* __restrict__ x)
{
  const int bs = blockIdx.x;
  const int d  = threadIdx.x;
  const int s  = bs & (S_-1);
  const int id = ids[bs];
  const int f  = (d < 128) ? (2*d) : (2*(d-128)+1);
  const float inv = powf(10000.f, -(float)f * (1.f/256.f));
  const float pe  = sinf((float)s * inv);
  x[(size_t)bs*D_ + d] = (bf16)(emb[(size_t)id*D_ + d] + pe);
}

// ---------------------------------------------------------------------------
// GEMM 128x64 tile, BK=32, 4 waves, global_load_lds staging (m97 pattern).
// ---------------------------------------------------------------------------
template<bool RELU, bool OUT_BF16>
__global__ __launch_bounds__(256) void gemm_bt(
    const bf16* __restrict__ A, const bf16* __restrict__ BT,
    const float* __restrict__ bias, void* __restrict__ C,
    int M, int N, int K)
{
  __shared__ bf16 As[128*32];   // 8 KB
  __shared__ bf16 Bs[64*32];    // 4 KB
  const int tid  = threadIdx.x;
  const int lane = tid & 63, wave = tid >> 6;
  const int quad = lane >> 4, l15 = lane & 15;
  const int m0 = blockIdx.x * 128;
  const int n0 = blockIdx.y * 64;
  const int wm = (wave & 1) * 64;
  const int wn = (wave >> 1) * 32;

  const bf16* a0 = A  + (size_t)m0 * K;
  const bf16* b0 = BT + (size_t)n0 * K;
  const int row = tid >> 2;                 // 0..63
  const int ch  = (tid & 3) * 8;            // 16B chunk within BK

  f32x4 acc[4][2] = {};

  for (int k0 = 0; k0 < K; k0 += 32) {
    __syncthreads();   // WAR: previous iter's frag reads done
    load_lds16(a0 + (size_t)row*K      + k0 + ch, (char*)As + (size_t)wave*1024);
    load_lds16(a0 + (size_t)(row+64)*K + k0 + ch, (char*)As + 4096 + (size_t)wave*1024);
    load_lds16(b0 + (size_t)row*K      + k0 + ch, (char*)Bs + (size_t)wave*1024);
    __syncthreads();   // vmcnt(0): DMA complete
    bf16x8 af[4], bfr[2];
    #pragma unroll
    for (int mt = 0; mt < 4; ++mt)
      af[mt] = *(const bf16x8*)(As + (wm + mt*16 + l15)*32 + quad*8);
    #pragma unroll
    for (int nt = 0; nt < 2; ++nt)
      bfr[nt] = *(const bf16x8*)(Bs + (wn + nt*16 + l15)*32 + quad*8);
    #pragma unroll
    for (int mt = 0; mt < 4; ++mt)
      #pragma unroll
      for (int nt = 0; nt < 2; ++nt)
        acc[mt][nt] = __builtin_amdgcn_mfma_f32_16x16x32_bf16(af[mt], bfr[nt], acc[mt][nt], 0, 0, 0);
  }

  #pragma unroll
  for (int nt = 0; nt < 2; ++nt) {
    const int n = n0 + wn + nt*16 + l15;
    const float bvs = bias[n];
    #pragma unroll
    for (int mt = 0; mt < 4; ++mt) {
      const int mr = m0 + wm + mt*16 + quad*4;
      #pragma unroll
      for (int r = 0; r < 4; ++r) {
        float v = acc[mt][nt][r] + bvs;
        if (RELU) v = fmaxf(v, 0.f);
        if (OUT_BF16) ((bf16*)C)[(size_t)(mr + r)*N + n] = (bf16)v;
        else          ((float*)C)[(size_t)(mr + r)*N + n] = v;
      }
    }
  }
}

// ---------------------------------------------------------------------------
// GEMM 64x64 tile, BK=32, 4 waves (each 32x32) — for small-N GEMMs (2 blk/CU).
// ---------------------------------------------------------------------------
template<bool RELU, bool OUT_BF16, bool NMASK>
__global__ __launch_bounds__(256) void gemm_bt64(
    const bf16* __restrict__ A, const bf16* __restrict__ BT,
    const float* __restrict__ bias, void* __restrict__ C,
    int M, int N, int K)
{
  __shared__ bf16 As[64*32];    // 4 KB
  __shared__ bf16 Bs[64*32];    // 4 KB
  const int tid  = threadIdx.x;
  const int lane = tid & 63, wave = tid >> 6;
  const int quad = lane >> 4, l15 = lane & 15;
  const int m0 = blockIdx.x * 64;
  const int n0 = blockIdx.y * 64;
  const int wm = (wave & 1) * 32;
  const int wn = (wave >> 1) * 32;

  const bf16* a0 = A  + (size_t)m0 * K;
  const bf16* b0 = BT + (size_t)n0 * K;
  const int row = tid >> 2;
  const int ch  = (tid & 3) * 8;

  f32x4 acc[2][2] = {};

  for (int k0 = 0; k0 < K; k0 += 32) {
    __syncthreads();
    load_lds16(a0 + (size_t)row*K + k0 + ch, (char*)As + (size_t)wave*1024);
    load_lds16(b0 + (size_t)row*K + k0 + ch, (char*)Bs + (size_t)wave*1024);
    __syncthreads();
    bf16x8 af[2], bfr[2];
    #pragma unroll
    for (int mt = 0; mt < 2; ++mt)
      af[mt] = *(const bf16x8*)(As + (wm + mt*16 + l15)*32 + quad*8);
    #pragma unroll
    for (int nt = 0; nt < 2; ++nt)
      bfr[nt] = *(const bf16x8*)(Bs + (wn + nt*16 + l15)*32 + quad*8);
    #pragma unroll
    for (int mt = 0; mt < 2; ++mt)
      #pragma unroll
      for (int nt = 0; nt < 2; ++nt)
        acc[mt][nt] = __builtin_amdgcn_mfma_f32_16x16x32_bf16(af[mt], bfr[nt], acc[mt][nt], 0, 0, 0);
  }

  #pragma unroll
  for (int nt = 0; nt < 2; ++nt) {
    const int n = n0 + wn + nt*16 + l15;
    if (NMASK && n >= N) continue;
    const float bvs = bias[n];
    #pragma unroll
    for (int mt = 0; mt < 2; ++mt) {
      const int mr = m0 + wm + mt*16 + quad*4;
      #pragma unroll
      for (int r = 0; r < 4; ++r) {
        float v = acc[mt][nt][r] + bvs;
        if (RELU) v = fmaxf(v, 0.f);
        if (OUT_BF16) ((bf16*)C)[(size_t)(mr + r)*N + n] = (bf16)v;
        else          ((float*)C)[(size_t)(mr + r)*N + n] = v;
      }
    }
  }
}

// ---------------------------------------------------------------------------
// Pack: qkv[row][768] -> qp[b][h][s][32], kp[b][h][s][32], vt[b][h][dh][s].
// grid (16,8,8), block 256
// ---------------------------------------------------------------------------
__global__ void pack_kernel(const bf16* __restrict__ qkv, bf16* __restrict__ qp,
                            bf16* __restrict__ kp, bf16* __restrict__ vt)
{
  __shared__ bf16 t[64][33];
  const int s0 = blockIdx.x * 64, h = blockIdx.y, b = blockIdx.z;
  const int tid = threadIdx.x;
  const size_t bh = (size_t)b*H_ + h;
  const int row = tid >> 2, ch = (tid & 3) * 8;

  const bf16x8 qv = *(const bf16x8*)(qkv + ((size_t)(b*S_ + s0 + row))*768 + h*DH_ + ch);
  *(bf16x8*)(qp + (bh*S_ + s0 + row)*DH_ + ch) = qv;
  const bf16x8 kv = *(const bf16x8*)(qkv + ((size_t)(b*S_ + s0 + row))*768 + 256 + h*DH_ + ch);
  *(bf16x8*)(kp + (bh*S_ + s0 + row)*DH_ + ch) = kv;

  const int dl = tid & 31, sl = tid >> 5;
  #pragma unroll
  for (int i = 0; i < 8; ++i) {
    const int s = sl + i*8;
    t[s][dl] = qkv[((size_t)b*S_ + s0 + s)*768 + 512 + h*DH_ + dl];
  }
  __syncthreads();
  const int ss = tid & 63, dd = tid >> 6;
  #pragma unroll
  for (int i = 0; i < 8; ++i) {
    const int d = dd + i*4;
    vt[(bh*DH_ + d)*S_ + s0 + ss] = t[ss][d];
  }
}

// ---------------------------------------------------------------------------
// Flash attention, causal. grid (16, H, B), block 256 = 4 independent waves.
// Wave w of block x handles q-strip sid = x + 16w (16 rows) — balanced load,
// no intra-loop barriers (P strip is per-wave).
// ---------------------------------------------------------------------------
__global__ __launch_bounds__(256) void attn_kernel(
    const bf16* __restrict__ qp, const bf16* __restrict__ kp,
    const bf16* __restrict__ vt, const int* __restrict__ tsl,
    bf16* __restrict__ out)
{
  const int h = blockIdx.y, b = blockIdx.z;
  const int lane = threadIdx.x & 63, wave = threadIdx.x >> 6;
  const int quad = lane >> 4, l15 = lane & 15;
  const int sid = blockIdx.x + wave*16;     // 0..63
  const int q0 = sid*16;
  const int len = tsl[b];

  __shared__ bf16 Pl[4][16*64];

  const size_t bh = (size_t)b*H_ + h;
  const bf16* qb = qp + bh*S_*DH_;
  const bf16* kb = kp + bh*S_*DH_;
  const bf16* vb = vt + bh*DH_*S_;

  const bf16x8 qf = *(const bf16x8*)(qb + (size_t)(q0 + l15)*DH_ + quad*8);

  const float NEG = -1e30f;
  float m_run[4], l_run[4], al[4];
  f32x4 o0 = {0.f,0.f,0.f,0.f}, o1 = {0.f,0.f,0.f,0.f};
  #pragma unroll
  for (int r = 0; r < 4; ++r) { m_run[r] = NEG; l_run[r] = 0.f; }

  const float scale = 0.17677669529663687f;  // 1/sqrt(32)
  const int nk = (sid >> 2) + 1;             // k-tiles of 64 covering k <= q0+15
  for (int ks = 0; ks < nk; ++ks) {
    const int k0 = ks*64;
    f32x4 s[4];
    #pragma unroll
    for (int nt = 0; nt < 4; ++nt) {
      const bf16x8 kf = *(const bf16x8*)(kb + (size_t)(k0 + nt*16 + l15)*DH_ + quad*8);
      const f32x4 z = {0.f,0.f,0.f,0.f};
      s[nt] = __builtin_amdgcn_mfma_f32_16x16x32_bf16(qf, kf, z, 0, 0, 0);
    }
    float mx[4];
    #pragma unroll
    for (int r = 0; r < 4; ++r) mx[r] = NEG;
    const int qrow0 = q0 + quad*4;
    #pragma unroll
    for (int nt = 0; nt < 4; ++nt) {
      const int kpos = k0 + nt*16 + l15;
      #pragma unroll
      for (int r = 0; r < 4; ++r) {
        const int qr = qrow0 + r;
        const bool ok = (kpos <= qr) && (kpos < len) && (qr < len);
        const float v = ok ? s[nt][r] * scale : NEG;
        s[nt][r] = v;
        mx[r] = fmaxf(mx[r], v);
      }
    }
    #pragma unroll
    for (int r = 0; r < 4; ++r) {
      float v = mx[r];
      v = fmaxf(v, __shfl_xor(v, 1));
      v = fmaxf(v, __shfl_xor(v, 2));
      v = fmaxf(v, __shfl_xor(v, 4));
      v = fmaxf(v, __shfl_xor(v, 8));
      const float mn = fmaxf(m_run[r], v);
      al[r] = (m_run[r] > -1e29f) ? __expf(m_run[r] - mn) : 0.f;
      m_run[r] = mn;
    }
    float ls[4] = {0.f,0.f,0.f,0.f};
    #pragma unroll
    for (int nt = 0; nt < 4; ++nt)
      #pragma unroll
      for (int r = 0; r < 4; ++r) {
        const float vv = s[nt][r];
        const float p = (vv > -1e29f && m_run[r] > -1e29f) ? __expf(vv - m_run[r]) : 0.f;
        s[nt][r] = p;
        ls[r] += p;
      }
    #pragma unroll
    for (int r = 0; r < 4; ++r) {
      float v = ls[r];
      v += __shfl_xor(v, 1);
      v += __shfl_xor(v, 2);
      v += __shfl_xor(v, 4);
      v += __shfl_xor(v, 8);
      l_run[r] = l_run[r]*al[r] + v;
      o0[r] *= al[r];
      o1[r] *= al[r];
    }
    bf16* pw = &Pl[wave][0];
    #pragma unroll
    for (int nt = 0; nt < 4; ++nt)
      #pragma unroll
      for (int r = 0; r < 4; ++r)
        pw[(quad*4+r)*64 + nt*16 + l15] = (bf16)s[nt][r];
    asm volatile("s_waitcnt lgkmcnt(0)" ::: "memory");   // in-wave P write->read
    #pragma unroll
    for (int kc = 0; kc < 2; ++kc) {
      const bf16x8 pf = *(const bf16x8*)(pw + l15*64 + kc*32 + quad*8);
      const bf16x8 vf0 = *(const bf16x8*)(vb + (size_t)l15*S_ + k0 + kc*32 + quad*8);
      o0 = __builtin_amdgcn_mfma_f32_16x16x32_bf16(pf, vf0, o0, 0, 0, 0);
      const bf16x8 vf1 = *(const bf16x8*)(vb + (size_t)(16 + l15)*S_ + k0 + kc*32 + quad*8);
      o1 = __builtin_amdgcn_mfma_f32_16x16x32_bf16(pf, vf1, o1, 0, 0, 0);
    }
  }
  bf16* ob = out + (size_t)b*S_*D_ + h*DH_;
  #pragma unroll
  for (int r = 0; r < 4; ++r) {
    const float inv = 1.f / fmaxf(l_run[r], 1e-30f);
    const size_t rowoff = (size_t)(q0 + quad*4 + r)*D_;
    ob[rowoff + l15]      = (bf16)(o0[r]*inv);
    ob[rowoff + 16 + l15] = (bf16)(o1[r]*inv);
  }
}

// ---------------------------------------------------------------------------
// x = LN(x + y)*g + be.  one wave per 256-wide row; block = 4 rows.
// ---------------------------------------------------------------------------
__global__ void addln_kernel(const bf16* x, const float* y,
                             const float* g, const float* be, bf16* xo)
{
  const int row  = blockIdx.x*4 + (threadIdx.x >> 6);
  const int lane = threadIdx.x & 63;
  const bf16*  xr = x + (size_t)row*D_ + lane*4;
  const float* yr = y + (size_t)row*D_ + lane*4;
  const ushort4 xs = *(const ushort4*)xr;
  const float4  yv = *(const float4*)yr;
  const float v0 = b2f(xs.x) + yv.x;
  const float v1 = b2f(xs.y) + yv.y;
  const float v2 = b2f(xs.z) + yv.z;
  const float v3 = b2f(xs.w) + yv.w;
  float sm = v0+v1+v2+v3;
  #pragma unroll
  for (int off = 1; off < 64; off <<= 1) sm += __shfl_xor(sm, off);
  const float mean = sm * (1.f/256.f);
  const float d0 = v0-mean, d1 = v1-mean, d2 = v2-mean, d3 = v3-mean;
  float qs = d0*d0 + d1*d1 + d2*d2 + d3*d3;
  #pragma unroll
  for (int off = 1; off < 64; off <<= 1) qs += __shfl_xor(qs, off);
  const float inv = rsqrtf(qs*(1.f/256.f) + 1e-5f);
  const float4 gv = *(const float4*)(g + lane*4);
  const float4 bv = *(const float4*)(be + lane*4);
  bf16 o0 = (bf16)(d0*inv*gv.x + bv.x);
  bf16 o1 = (bf16)(d1*inv*gv.y + bv.y);
  bf16 o2 = (bf16)(d2*inv*gv.z + bv.z);
  bf16 o3 = (bf16)(d3*inv*gv.w + bv.w);
  ushort4 ov = { *(unsigned short*)&o0, *(unsigned short*)&o1,
                 *(unsigned short*)&o2, *(unsigned short*)&o3 };
  *(ushort4*)(xo + (size_t)row*D_ + lane*4) = ov;
}

// ---------------------------------------------------------------------------
extern "C" void kernel_launch(void* const* d_in, const int* in_sizes, int n_in,
                              void* d_out, int out_size, void* d_ws, size_t ws_size,
                              hipStream_t stream)
{
  const int*   ids = (const int*)d_in[0];
  const int*   tsl = (const int*)d_in[1];
  const float* emb = (const float*)d_in[2];
  const float* Wq  = (const float*)d_in[3];
  const float* bq  = (const float*)d_in[4];
  const float* Wk  = (const float*)d_in[5];
  const float* bk  = (const float*)d_in[6];
  const float* Wv  = (const float*)d_in[7];
  const float* bv  = (const float*)d_in[8];
  const float* Wo  = (const float*)d_in[9];
  const float* bo  = (const float*)d_in[10];
  const float* W1  = (const float*)d_in[11];
  const float* b1  = (const float*)d_in[12];
  const float* W2  = (const float*)d_in[13];
  const float* b2  = (const float*)d_in[14];
  const float* g1  = (const float*)d_in[15];
  const float* be1 = (const float*)d_in[16];
  const float* g2  = (const float*)d_in[17];
  const float* be2 = (const float*)d_in[18];
  const float* Wc  = (const float*)d_in[19];
  const float* bc  = (const float*)d_in[20];

  if (ws_size < (size_t)40*1024*1024) return;   // trips -> absmax 1.65625

  char* p = (char*)d_ws;
  auto carve = [&](size_t bytes) { void* r = (void*)p; p += (bytes + 255) & ~(size_t)255; return r; };
  bf16*  x     = (bf16*) carve((size_t)M_*D_*2);        // 4 MB, persistent
  char*  big   = (char*) carve((size_t)M_*DFF_*2);      // 16 MB: qkv | attn-out | ff1
  char*  pkbuf = (char*) carve((size_t)3*M_*DH_*H_*2 > (size_t)M_*D_*4
                               ? (size_t)3*M_*DH_*H_*2 : (size_t)M_*D_*4);  // 12 MB: qp+kp+vt | yf
  bf16*  WqkvT = (bf16*) carve((size_t)L_*768*256*2);
  bf16*  WoT   = (bf16*) carve((size_t)L_*65536*2);
  bf16*  W1T   = (bf16*) carve((size_t)L_*262144*2);
  bf16*  W2T   = (bf16*) carve((size_t)L_*262144*2);
  bf16*  WcT   = (bf16*) carve((size_t)128*256*2);
  float* bqkv  = (float*)carve((size_t)L_*768*4);

  bf16*  qkv  = (bf16*)big;                       // [8192][768], dead after pack
  bf16*  aout = (bf16*)big;                       // [8192][256], pack->WO (reuses qkv)
  bf16*  ff1  = (bf16*)big;                       // [8192][1024], FF1->FF2
  bf16*  qp   = (bf16*)pkbuf;                     // 4 MB
  bf16*  kp   = (bf16*)(pkbuf + (size_t)M_*DH_*H_/8*2*8/8 + 0) + 0;  // laid out below
  kp = (bf16*)(pkbuf + (size_t)2*1024*1024*2);    // +4 MB
  bf16*  vt   = (bf16*)(pkbuf + (size_t)4*1024*1024*2);  // +8 MB
  float* yf   = (float*)pkbuf;                    // 8 MB, WO/FF2 -> addln (qp/kp dead)

  prep_kernel<<<dim3(1024,6,4), 256, 0, stream>>>(Wq,Wk,Wv,Wo,W1,W2,Wc,bq,bk,bv,
                                                  WqkvT,WoT,W1T,W2T,WcT,bqkv);
  embed_kernel<<<dim3(M_), 256, 0, stream>>>(ids, emb, x);

  for (int l = 0; l < L_; ++l) {
    gemm_bt<false,true><<<dim3(64,12), 256, 0, stream>>>(
        x, WqkvT + (size_t)l*768*256, bqkv + l*768, qkv, M_, 768, 256);
    pack_kernel<<<dim3(16,8,8), 256, 0, stream>>>(qkv, qp, kp, vt);
    attn_kernel<<<dim3(16,8,8), 256, 0, stream>>>(qp, kp, vt, tsl, aout);
    gemm_bt64<false,false,false><<<dim3(128,4), 256, 0, stream>>>(
        aout, WoT + (size_t)l*65536, bo + l*256, yf, M_, 256, 256);
    addln_kernel<<<dim3(2048), 256, 0, stream>>>(x, yf, g1 + l*256, be1 + l*256, x);
    gemm_bt<true,true><<<dim3(64,16), 256, 0, stream>>>(
        x, W1T + (size_t)l*262144, b1 + l*1024, ff1, M_, 1024, 256);
    gemm_bt64<false,false,false><<<dim3(128,4), 256, 0, stream>>>(
        ff1, W2T + (size_t)l*262144, b2 + l*256, yf, M_, 256, 1024);
    addln_kernel<<<dim3(2048), 256, 0, stream>>>(x, yf, g2 + l*256, be2 + l*256, x);
  }

  gemm_bt64<false,false,true><<<dim3(128,2), 256, 0, stream>>>(
      x, WcT, bc, (float*)d_out, M_, V_, 256);
}

// Round 6
// 485.699 us; speedup vs baseline: 1.2707x; 1.0716x over previous
//
#include <hip/hip_runtime.h>
#include <hip/hip_bf16.h>
#include <stdint.h>

#define B_   8
#define S_   1024
#define D_   256
#define H_   8
#define DH_  32
#define L_   4
#define V_   100
#define DFF_ 1024
#define M_   (B_*S_)   // 8192

using bf16 = __hip_bfloat16;
typedef __bf16 bf16x8 __attribute__((ext_vector_type(8)));
typedef float  f32x4  __attribute__((ext_vector_type(4)));

static __device__ __forceinline__ float b2f(unsigned short u) {
  union { unsigned int i; float f; } w; w.i = ((unsigned int)u) << 16; return w.f;
}

// async global->LDS DMA: 16B/lane, LDS dest = wave-uniform base + lane*16
static __device__ __forceinline__ void load_lds16(const void* g, void* l) {
  __builtin_amdgcn_global_load_lds((const __attribute__((address_space(1))) void*)g,
                                   (__attribute__((address_space(3))) void*)l,
                                   16, 0, 0);
}

// DPP cross-lane (VALU-speed, replaces ds_swizzle shuffles).
// Reduction domain = 16-lane DPP row == our l15 group.
template<int CTRL>
static __device__ __forceinline__ float dppf(float v) {
  union { float f; int i; } a, r;
  a.f = v;
  r.i = __builtin_amdgcn_update_dpp(0, a.i, CTRL, 0xF, 0xF, true);
  return r.f;
}
static __device__ __forceinline__ float red_max16(float v) {
  v = fmaxf(v, dppf<0xB1>(v));    // quad_perm [1,0,3,2]
  v = fmaxf(v, dppf<0x4E>(v));    // quad_perm [2,3,0,1]
  v = fmaxf(v, dppf<0x141>(v));   // row_half_mirror
  v = fmaxf(v, dppf<0x140>(v));   // row_mirror
  return v;
}
static __device__ __forceinline__ float red_sum16(float v) {
  v += dppf<0xB1>(v);
  v += dppf<0x4E>(v);
  v += dppf<0x141>(v);
  v += dppf<0x140>(v);
  return v;
}

// ---------------------------------------------------------------------------
// Tiled weight prep: f32 [R][C] -> bf16 [C][R], 32x32 LDS tiles, coalesced
// both directions. grid (32,32,26), block (32,8).
// jobs 0..11 QKV (l*3+which), 12..15 Wo, 16..19 W1, 20..23 W2, 24 Wc, 25 bias
// ---------------------------------------------------------------------------
__global__ void prep_t(const float* __restrict__ Wq, const float* __restrict__ Wk,
                       const float* __restrict__ Wv, const float* __restrict__ Wo,
                       const float* __restrict__ W1, const float* __restrict__ W2,
                       const float* __restrict__ Wc,
                       const float* __restrict__ bq, const float* __restrict__ bk,
                       const float* __restrict__ bv,
                       bf16* __restrict__ WqkvT, bf16* __restrict__ WoT,
                       bf16* __restrict__ W1T, bf16* __restrict__ W2T,
                       bf16* __restrict__ WcT, float* __restrict__ bqkv)
{
  const int z = blockIdx.z;
  if (z == 25) {                                 // fused qkv bias
    if (blockIdx.x || blockIdx.y) return;
    const int tid = threadIdx.y*32 + threadIdx.x;
    for (int i = tid; i < L_*768; i += 256) {
      const int l2 = i / 768, j = i % 768;
      const float* src = (j < 256) ? bq : (j < 512) ? bk : bv;
      bqkv[i] = src[l2*256 + (j & 255)];
    }
    return;
  }
  const float* src; bf16* dst; int R, C, Cd;
  if (z < 12) {
    const int l = z / 3, w = z % 3;
    src = ((w == 0) ? Wq : (w == 1) ? Wk : Wv) + (size_t)l*65536;
    R = 256; C = 256; Cd = 256;
    dst = WqkvT + (size_t)l*196608 + (size_t)w*65536;
  } else if (z < 16) {
    const int l = z - 12;
    src = Wo + (size_t)l*65536; R = 256; C = 256; Cd = 256;
    dst = WoT + (size_t)l*65536;
  } else if (z < 20) {
    const int l = z - 16;
    src = W1 + (size_t)l*262144; R = 256; C = 1024; Cd = 1024;
    dst = W1T + (size_t)l*262144;
  } else if (z < 24) {
    const int l = z - 20;
    src = W2 + (size_t)l*262144; R = 1024; C = 256; Cd = 256;
    dst = W2T + (size_t)l*262144;
  } else {
    src = Wc; R = 256; C = 100; Cd = 128;        // pad rows 100..127 with 0
    dst = WcT;
  }
  const int c0 = blockIdx.x*32, r0 = blockIdx.y*32;
  if (c0 >= Cd || r0 >= R) return;
  __shared__ float t[32][33];
  #pragma unroll
  for (int i = 0; i < 4; ++i) {
    const int r = r0 + threadIdx.y + i*8;
    const int c = c0 + threadIdx.x;
    t[threadIdx.y + i*8][threadIdx.x] = (r < R && c < C) ? src[(size_t)r*C + c] : 0.f;
  }
  __syncthreads();
  #pragma unroll
  for (int i = 0; i < 4; ++i) {
    const int c = c0 + threadIdx.y + i*8;        // dst row
    const int r = r0 + threadIdx.x;              // dst col
    if (c < Cd && r < R)
      dst[(size_t)c*R + r] = (bf16)t[threadIdx.x][threadIdx.y + i*8];
  }
}

// ---------------------------------------------------------------------------
__global__ void embed_kernel(const int* __restrict__ ids, const float* __restrict__ emb,
                             bf16* __restrict__ x)
{
  const int bs = blockIdx.x;
  const int d  = threadIdx.x;
  const int s  = bs & (S_-1);
  const int id = ids[bs];
  const int f  = (d < 128) ? (2*d) : (2*(d-128)+1);
  const float inv = powf(10000.f, -(float)f * (1.f/256.f));
  const float pe  = sinf((float)s * inv);
  x[(size_t)bs*D_ + d] = (bf16)(emb[(size_t)id*D_ + d] + pe);
}

// ---------------------------------------------------------------------------
// QKV GEMM with packed epilogue: writes qp[bh][s][32], kp[bh][s][32],
// vt[bh][d][s] directly (no intermediate qkv, no pack kernel).
// 128x64 tile, BK=32, grid (64,12).
// ---------------------------------------------------------------------------
__global__ __launch_bounds__(256) void gemm_qkv(
    const bf16* __restrict__ A, const bf16* __restrict__ BT,
    const float* __restrict__ bias,
    bf16* __restrict__ qp, bf16* __restrict__ kp, bf16* __restrict__ vt)
{
  __shared__ bf16 As[128*32];   // 8 KB
  __shared__ bf16 Bs[64*32];    // 4 KB
  __shared__ bf16 Vs[64][136];  // 17 KB, epilogue V transpose
  const int tid  = threadIdx.x;
  const int lane = tid & 63, wave = tid >> 6;
  const int quad = lane >> 4, l15 = lane & 15;
  const int m0 = blockIdx.x * 128;
  const int n0 = blockIdx.y * 64;
  const int wm = (wave & 1) * 64;
  const int wn = (wave >> 1) * 32;
  const int K = 256;

  const bf16* a0 = A  + (size_t)m0 * K;
  const bf16* b0 = BT + (size_t)n0 * K;
  const int row = tid >> 2;
  const int ch  = (tid & 3) * 8;

  f32x4 acc[4][2] = {};

  for (int k0 = 0; k0 < K; k0 += 32) {
    __syncthreads();
    load_lds16(a0 + (size_t)row*K      + k0 + ch, (char*)As + (size_t)wave*1024);
    load_lds16(a0 + (size_t)(row+64)*K + k0 + ch, (char*)As + 4096 + (size_t)wave*1024);
    load_lds16(b0 + (size_t)row*K      + k0 + ch, (char*)Bs + (size_t)wave*1024);
    __syncthreads();
    bf16x8 af[4], bfr[2];
    #pragma unroll
    for (int mt = 0; mt < 4; ++mt)
      af[mt] = *(const bf16x8*)(As + (wm + mt*16 + l15)*32 + quad*8);
    #pragma unroll
    for (int nt = 0; nt < 2; ++nt)
      bfr[nt] = *(const bf16x8*)(Bs + (wn + nt*16 + l15)*32 + quad*8);
    #pragma unroll
    for (int mt = 0; mt < 4; ++mt)
      #pragma unroll
      for (int nt = 0; nt < 2; ++nt)
        acc[mt][nt] = __builtin_amdgcn_mfma_f32_16x16x32_bf16(af[mt], bfr[nt], acc[mt][nt], 0, 0, 0);
  }

  const int seg = n0 >> 8;            // 0=Q, 1=K, 2=V
  const int b  = m0 >> 10;
  const int s0 = m0 & 1023;

  if (seg < 2) {
    bf16* dst = seg ? kp : qp;
    #pragma unroll
    for (int nt = 0; nt < 2; ++nt) {
      const int n  = n0 + wn + nt*16 + l15;
      const int nn = n & 255;
      const int h = nn >> 5, d = nn & 31;
      const float bvs = bias[n];
      bf16* hb = dst + (((size_t)b*H_ + h)*S_)*DH_ + d;
      #pragma unroll
      for (int mt = 0; mt < 4; ++mt) {
        const int ml = wm + mt*16 + quad*4;
        #pragma unroll
        for (int r = 0; r < 4; ++r)
          hb[(size_t)(s0 + ml + r)*DH_] = (bf16)(acc[mt][nt][r] + bvs);
      }
    }
  } else {
    #pragma unroll
    for (int nt = 0; nt < 2; ++nt) {
      const int nl = wn + nt*16 + l15;
      const float bvs = bias[n0 + nl];
      #pragma unroll
      for (int mt = 0; mt < 4; ++mt) {
        const int ml = wm + mt*16 + quad*4;
        #pragma unroll
        for (int r = 0; r < 4; ++r)
          Vs[nl][ml + r] = (bf16)(acc[mt][nt][r] + bvs);
      }
    }
    __syncthreads();
    #pragma unroll
    for (int t = 0; t < 2; ++t) {
      const int vrow = (tid >> 3) + 32*t;        // 0..63
      const int soff = (tid & 7) * 16;           // 0..112
      const int nn = (n0 + vrow) & 255;
      const int h = nn >> 5, d = nn & 31;
      bf16* dst = vt + (((size_t)b*H_ + h)*DH_ + d)*S_ + s0 + soff;
      *(bf16x8*)dst       = *(const bf16x8*)&Vs[vrow][soff];
      *(bf16x8*)(dst + 8) = *(const bf16x8*)&Vs[vrow][soff + 8];
    }
  }
}

// ---------------------------------------------------------------------------
// Generic GEMM 128x64 tile (bias, optional relu), used for FF1.
// ---------------------------------------------------------------------------
template<bool RELU, bool OUT_BF16>
__global__ __launch_bounds__(256) void gemm_bt(
    const bf16* __restrict__ A, const bf16* __restrict__ BT,
    const float* __restrict__ bias, void* __restrict__ C,
    int M, int N, int K)
{
  __shared__ bf16 As[128*32];
  __shared__ bf16 Bs[64*32];
  const int tid  = threadIdx.x;
  const int lane = tid & 63, wave = tid >> 6;
  const int quad = lane >> 4, l15 = lane & 15;
  const int m0 = blockIdx.x * 128;
  const int n0 = blockIdx.y * 64;
  const int wm = (wave & 1) * 64;
  const int wn = (wave >> 1) * 32;

  const bf16* a0 = A  + (size_t)m0 * K;
  const bf16* b0 = BT + (size_t)n0 * K;
  const int row = tid >> 2;
  const int ch  = (tid & 3) * 8;

  f32x4 acc[4][2] = {};

  for (int k0 = 0; k0 < K; k0 += 32) {
    __syncthreads();
    load_lds16(a0 + (size_t)row*K      + k0 + ch, (char*)As + (size_t)wave*1024);
    load_lds16(a0 + (size_t)(row+64)*K + k0 + ch, (char*)As + 4096 + (size_t)wave*1024);
    load_lds16(b0 + (size_t)row*K      + k0 + ch, (char*)Bs + (size_t)wave*1024);
    __syncthreads();
    bf16x8 af[4], bfr[2];
    #pragma unroll
    for (int mt = 0; mt < 4; ++mt)
      af[mt] = *(const bf16x8*)(As + (wm + mt*16 + l15)*32 + quad*8);
    #pragma unroll
    for (int nt = 0; nt < 2; ++nt)
      bfr[nt] = *(const bf16x8*)(Bs + (wn + nt*16 + l15)*32 + quad*8);
    #pragma unroll
    for (int mt = 0; mt < 4; ++mt)
      #pragma unroll
      for (int nt = 0; nt < 2; ++nt)
        acc[mt][nt] = __builtin_amdgcn_mfma_f32_16x16x32_bf16(af[mt], bfr[nt], acc[mt][nt], 0, 0, 0);
  }

  #pragma unroll
  for (int nt = 0; nt < 2; ++nt) {
    const int n = n0 + wn + nt*16 + l15;
    const float bvs = bias[n];
    #pragma unroll
    for (int mt = 0; mt < 4; ++mt) {
      const int mr = m0 + wm + mt*16 + quad*4;
      #pragma unroll
      for (int r = 0; r < 4; ++r) {
        float v = acc[mt][nt][r] + bvs;
        if (RELU) v = fmaxf(v, 0.f);
        if (OUT_BF16) ((bf16*)C)[(size_t)(mr + r)*N + n] = (bf16)v;
        else          ((float*)C)[(size_t)(mr + r)*N + n] = v;
      }
    }
  }
}

// ---------------------------------------------------------------------------
// GEMM 64x64 tile — for N=256/128 GEMMs (WO, FF2, classifier).
// ---------------------------------------------------------------------------
template<bool RELU, bool OUT_BF16, bool NMASK>
__global__ __launch_bounds__(256) void gemm_bt64(
    const bf16* __restrict__ A, const bf16* __restrict__ BT,
    const float* __restrict__ bias, void* __restrict__ C,
    int M, int N, int K)
{
  __shared__ bf16 As[64*32];
  __shared__ bf16 Bs[64*32];
  const int tid  = threadIdx.x;
  const int lane = tid & 63, wave = tid >> 6;
  const int quad = lane >> 4, l15 = lane & 15;
  const int m0 = blockIdx.x * 64;
  const int n0 = blockIdx.y * 64;
  const int wm = (wave & 1) * 32;
  const int wn = (wave >> 1) * 32;

  const bf16* a0 = A  + (size_t)m0 * K;
  const bf16* b0 = BT + (size_t)n0 * K;
  const int row = tid >> 2;
  const int ch  = (tid & 3) * 8;

  f32x4 acc[2][2] = {};

  for (int k0 = 0; k0 < K; k0 += 32) {
    __syncthreads();
    load_lds16(a0 + (size_t)row*K + k0 + ch, (char*)As + (size_t)wave*1024);
    load_lds16(b0 + (size_t)row*K + k0 + ch, (char*)Bs + (size_t)wave*1024);
    __syncthreads();
    bf16x8 af[2], bfr[2];
    #pragma unroll
    for (int mt = 0; mt < 2; ++mt)
      af[mt] = *(const bf16x8*)(As + (wm + mt*16 + l15)*32 + quad*8);
    #pragma unroll
    for (int nt = 0; nt < 2; ++nt)
      bfr[nt] = *(const bf16x8*)(Bs + (wn + nt*16 + l15)*32 + quad*8);
    #pragma unroll
    for (int mt = 0; mt < 2; ++mt)
      #pragma unroll
      for (int nt = 0; nt < 2; ++nt)
        acc[mt][nt] = __builtin_amdgcn_mfma_f32_16x16x32_bf16(af[mt], bfr[nt], acc[mt][nt], 0, 0, 0);
  }

  #pragma unroll
  for (int nt = 0; nt < 2; ++nt) {
    const int n = n0 + wn + nt*16 + l15;
    if (NMASK && n >= N) continue;
    const float bvs = bias[n];
    #pragma unroll
    for (int mt = 0; mt < 2; ++mt) {
      const int mr = m0 + wm + mt*16 + quad*4;
      #pragma unroll
      for (int r = 0; r < 4; ++r) {
        float v = acc[mt][nt][r] + bvs;
        if (RELU) v = fmaxf(v, 0.f);
        if (OUT_BF16) ((bf16*)C)[(size_t)(mr + r)*N + n] = (bf16)v;
        else          ((float*)C)[(size_t)(mr + r)*N + n] = v;
      }
    }
  }
}

// ---------------------------------------------------------------------------
// Flash attention, causal. grid (16, H, B), block 256 = 4 independent waves.
// Wave w of block x owns q-strip sid = x + 16w (balanced; no intra-loop
// barriers). Fast path for len >= S: mask only the diagonal tile, DPP
// reductions, unguarded exp (sentinel -1e30 is exp-safe).
// ---------------------------------------------------------------------------
__global__ __launch_bounds__(256) void attn_kernel(
    const bf16* __restrict__ qp, const bf16* __restrict__ kp,
    const bf16* __restrict__ vt, const int* __restrict__ tsl,
    bf16* __restrict__ out)
{
  const int h = blockIdx.y, b = blockIdx.z;
  const int lane = threadIdx.x & 63, wave = threadIdx.x >> 6;
  const int quad = lane >> 4, l15 = lane & 15;
  const int sid = blockIdx.x + wave*16;     // 0..63
  const int q0 = sid*16;
  const int len = tsl[b];

  __shared__ bf16 Pl[4][16*64];

  const size_t bh = (size_t)b*H_ + h;
  const bf16* qb = qp + bh*S_*DH_;
  const bf16* kb = kp + bh*S_*DH_;
  const bf16* vb = vt + bh*DH_*S_;

  const bf16x8 qf = *(const bf16x8*)(qb + (size_t)(q0 + l15)*DH_ + quad*8);

  const float NEG = -1e30f;
  float m_run[4], l_run[4], al[4];
  f32x4 o0 = {0.f,0.f,0.f,0.f}, o1 = {0.f,0.f,0.f,0.f};
  #pragma unroll
  for (int r = 0; r < 4; ++r) { m_run[r] = NEG; l_run[r] = 0.f; }

  const float scale = 0.17677669529663687f;  // 1/sqrt(32)
  bf16* pw = &Pl[wave][0];
  const int qrow0 = q0 + quad*4;

  if (len >= S_) {
    // ---- fast path: every row has unmasked positions; only diagonal tile
    // needs the causal compare.
    const int dt = sid >> 2;
    for (int ks = 0; ks <= dt; ++ks) {
      const int k0 = ks*64;
      f32x4 s[4];
      #pragma unroll
      for (int nt = 0; nt < 4; ++nt) {
        const bf16x8 kf = *(const bf16x8*)(kb + (size_t)(k0 + nt*16 + l15)*DH_ + quad*8);
        const f32x4 z = {0.f,0.f,0.f,0.f};
        s[nt] = __builtin_amdgcn_mfma_f32_16x16x32_bf16(qf, kf, z, 0, 0, 0);
      }
      float mx[4];
      if (ks == dt) {
        #pragma unroll
        for (int r = 0; r < 4; ++r) mx[r] = NEG;
        #pragma unroll
        for (int nt = 0; nt < 4; ++nt) {
          const int kpos = k0 + nt*16 + l15;
          #pragma unroll
          for (int r = 0; r < 4; ++r) {
            const float v = (kpos <= qrow0 + r) ? s[nt][r] * scale : NEG;
            s[nt][r] = v;
            mx[r] = fmaxf(mx[r], v);
          }
        }
      } else {
        #pragma unroll
        for (int r = 0; r < 4; ++r) {
          float v0 = s[0][r] * scale; s[0][r] = v0;
          float v1 = s[1][r] * scale; s[1][r] = v1;
          float v2 = s[2][r] * scale; s[2][r] = v2;
          float v3 = s[3][r] * scale; s[3][r] = v3;
          mx[r] = fmaxf(fmaxf(v0, v1), fmaxf(v2, v3));
        }
      }
      #pragma unroll
      for (int r = 0; r < 4; ++r) {
        const float mn = fmaxf(m_run[r], red_max16(mx[r]));
        al[r] = __expf(m_run[r] - mn);   // first iter: exp(-1e30-mn)=0, finite
        m_run[r] = mn;
      }
      float ls[4];
      #pragma unroll
      for (int r = 0; r < 4; ++r) {
        float p0 = __expf(s[0][r] - m_run[r]); s[0][r] = p0;
        float p1 = __expf(s[1][r] - m_run[r]); s[1][r] = p1;
        float p2 = __expf(s[2][r] - m_run[r]); s[2][r] = p2;
        float p3 = __expf(s[3][r] - m_run[r]); s[3][r] = p3;
        ls[r] = (p0 + p1) + (p2 + p3);
      }
      #pragma unroll
      for (int r = 0; r < 4; ++r) {
        l_run[r] = l_run[r]*al[r] + red_sum16(ls[r]);
        o0[r] *= al[r];
        o1[r] *= al[r];
      }
      #pragma unroll
      for (int nt = 0; nt < 4; ++nt)
        #pragma unroll
        for (int r = 0; r < 4; ++r)
          pw[(quad*4+r)*64 + nt*16 + l15] = (bf16)s[nt][r];
      asm volatile("s_waitcnt lgkmcnt(0)" ::: "memory");
      #pragma unroll
      for (int kc = 0; kc < 2; ++kc) {
        const bf16x8 pf = *(const bf16x8*)(pw + l15*64 + kc*32 + quad*8);
        const bf16x8 vf0 = *(const bf16x8*)(vb + (size_t)l15*S_ + k0 + kc*32 + quad*8);
        o0 = __builtin_amdgcn_mfma_f32_16x16x32_bf16(pf, vf0, o0, 0, 0, 0);
        const bf16x8 vf1 = *(const bf16x8*)(vb + (size_t)(16 + l15)*S_ + k0 + kc*32 + quad*8);
        o1 = __builtin_amdgcn_mfma_f32_16x16x32_bf16(pf, vf1, o1, 0, 0, 0);
      }
    }
  } else {
    // ---- slow path: arbitrary len (guarded exps, full masking)
    const int nk = (sid >> 2) + 1;
    for (int ks = 0; ks < nk; ++ks) {
      const int k0 = ks*64;
      f32x4 s[4];
      #pragma unroll
      for (int nt = 0; nt < 4; ++nt) {
        const bf16x8 kf = *(const bf16x8*)(kb + (size_t)(k0 + nt*16 + l15)*DH_ + quad*8);
        const f32x4 z = {0.f,0.f,0.f,0.f};
        s[nt] = __builtin_amdgcn_mfma_f32_16x16x32_bf16(qf, kf, z, 0, 0, 0);
      }
      float mx[4];
      #pragma unroll
      for (int r = 0; r < 4; ++r) mx[r] = NEG;
      #pragma unroll
      for (int nt = 0; nt < 4; ++nt) {
        const int kpos = k0 + nt*16 + l15;
        #pragma unroll
        for (int r = 0; r < 4; ++r) {
          const int qr = qrow0 + r;
          const bool ok = (kpos <= qr) && (kpos < len) && (qr < len);
          const float v = ok ? s[nt][r] * scale : NEG;
          s[nt][r] = v;
          mx[r] = fmaxf(mx[r], v);
        }
      }
      #pragma unroll
      for (int r = 0; r < 4; ++r) {
        const float mn = fmaxf(m_run[r], red_max16(mx[r]));
        al[r] = (m_run[r] > -1e29f) ? __expf(m_run[r] - mn) : 0.f;
        m_run[r] = mn;
      }
      float ls[4] = {0.f,0.f,0.f,0.f};
      #pragma unroll
      for (int nt = 0; nt < 4; ++nt)
        #pragma unroll
        for (int r = 0; r < 4; ++r) {
          const float vv = s[nt][r];
          const float p = (vv > -1e29f && m_run[r] > -1e29f) ? __expf(vv - m_run[r]) : 0.f;
          s[nt][r] = p;
          ls[r] += p;
        }
      #pragma unroll
      for (int r = 0; r < 4; ++r) {
        l_run[r] = l_run[r]*al[r] + red_sum16(ls[r]);
        o0[r] *= al[r];
        o1[r] *= al[r];
      }
      #pragma unroll
      for (int nt = 0; nt < 4; ++nt)
        #pragma unroll
        for (int r = 0; r < 4; ++r)
          pw[(quad*4+r)*64 + nt*16 + l15] = (bf16)s[nt][r];
      asm volatile("s_waitcnt lgkmcnt(0)" ::: "memory");
      #pragma unroll
      for (int kc = 0; kc < 2; ++kc) {
        const bf16x8 pf = *(const bf16x8*)(pw + l15*64 + kc*32 + quad*8);
        const bf16x8 vf0 = *(const bf16x8*)(vb + (size_t)l15*S_ + k0 + kc*32 + quad*8);
        o0 = __builtin_amdgcn_mfma_f32_16x16x32_bf16(pf, vf0, o0, 0, 0, 0);
        const bf16x8 vf1 = *(const bf16x8*)(vb + (size_t)(16 + l15)*S_ + k0 + kc*32 + quad*8);
        o1 = __builtin_amdgcn_mfma_f32_16x16x32_bf16(pf, vf1, o1, 0, 0, 0);
      }
    }
  }

  bf16* ob = out + (size_t)b*S_*D_ + h*DH_;
  #pragma unroll
  for (int r = 0; r < 4; ++r) {
    const float inv = 1.f / fmaxf(l_run[r], 1e-30f);
    const size_t rowoff = (size_t)(q0 + quad*4 + r)*D_;
    ob[rowoff + l15]      = (bf16)(o0[r]*inv);
    ob[rowoff + 16 + l15] = (bf16)(o1[r]*inv);
  }
}

// ---------------------------------------------------------------------------
// x = LN(x + y)*g + be.  one wave per 256-wide row; block = 4 rows.
// ---------------------------------------------------------------------------
__global__ void addln_kernel(const bf16* x, const float* y,
                             const float* g, const float* be, bf16* xo)
{
  const int row  = blockIdx.x*4 + (threadIdx.x >> 6);
  const int lane = threadIdx.x & 63;
  const bf16*  xr = x + (size_t)row*D_ + lane*4;
  const float* yr = y + (size_t)row*D_ + lane*4;
  const ushort4 xs = *(const ushort4*)xr;
  const float4  yv = *(const float4*)yr;
  const float v0 = b2f(xs.x) + yv.x;
  const float v1 = b2f(xs.y) + yv.y;
  const float v2 = b2f(xs.z) + yv.z;
  const float v3 = b2f(xs.w) + yv.w;
  float sm = v0+v1+v2+v3;
  #pragma unroll
  for (int off = 1; off < 64; off <<= 1) sm += __shfl_xor(sm, off);
  const float mean = sm * (1.f/256.f);
  const float d0 = v0-mean, d1 = v1-mean, d2 = v2-mean, d3 = v3-mean;
  float qs = d0*d0 + d1*d1 + d2*d2 + d3*d3;
  #pragma unroll
  for (int off = 1; off < 64; off <<= 1) qs += __shfl_xor(qs, off);
  const float inv = rsqrtf(qs*(1.f/256.f) + 1e-5f);
  const float4 gv = *(const float4*)(g + lane*4);
  const float4 bv = *(const float4*)(be + lane*4);
  bf16 o0 = (bf16)(d0*inv*gv.x + bv.x);
  bf16 o1 = (bf16)(d1*inv*gv.y + bv.y);
  bf16 o2 = (bf16)(d2*inv*gv.z + bv.z);
  bf16 o3 = (bf16)(d3*inv*gv.w + bv.w);
  ushort4 ov = { *(unsigned short*)&o0, *(unsigned short*)&o1,
                 *(unsigned short*)&o2, *(unsigned short*)&o3 };
  *(ushort4*)(xo + (size_t)row*D_ + lane*4) = ov;
}

// ---------------------------------------------------------------------------
extern "C" void kernel_launch(void* const* d_in, const int* in_sizes, int n_in,
                              void* d_out, int out_size, void* d_ws, size_t ws_size,
                              hipStream_t stream)
{
  const int*   ids = (const int*)d_in[0];
  const int*   tsl = (const int*)d_in[1];
  const float* emb = (const float*)d_in[2];
  const float* Wq  = (const float*)d_in[3];
  const float* bq  = (const float*)d_in[4];
  const float* Wk  = (const float*)d_in[5];
  const float* bk  = (const float*)d_in[6];
  const float* Wv  = (const float*)d_in[7];
  const float* bv  = (const float*)d_in[8];
  const float* Wo  = (const float*)d_in[9];
  const float* bo  = (const float*)d_in[10];
  const float* W1  = (const float*)d_in[11];
  const float* b1  = (const float*)d_in[12];
  const float* W2  = (const float*)d_in[13];
  const float* b2  = (const float*)d_in[14];
  const float* g1  = (const float*)d_in[15];
  const float* be1 = (const float*)d_in[16];
  const float* g2  = (const float*)d_in[17];
  const float* be2 = (const float*)d_in[18];
  const float* Wc  = (const float*)d_in[19];
  const float* bc  = (const float*)d_in[20];

  if (ws_size < (size_t)40*1024*1024) return;

  char* p = (char*)d_ws;
  auto carve = [&](size_t bytes) { void* r = (void*)p; p += (bytes + 255) & ~(size_t)255; return r; };
  bf16*  x     = (bf16*) carve((size_t)M_*D_*2);        // 4 MB, persistent
  char*  big   = (char*) carve((size_t)M_*DFF_*2);      // 16 MB: aout | ff1
  char*  pkbuf = (char*) carve((size_t)12*1024*1024);   // 12 MB: qp+kp+vt | yf
  bf16*  WqkvT = (bf16*) carve((size_t)L_*768*256*2);
  bf16*  WoT   = (bf16*) carve((size_t)L_*65536*2);
  bf16*  W1T   = (bf16*) carve((size_t)L_*262144*2);
  bf16*  W2T   = (bf16*) carve((size_t)L_*262144*2);
  bf16*  WcT   = (bf16*) carve((size_t)128*256*2);
  float* bqkv  = (float*)carve((size_t)L_*768*4);

  bf16*  aout = (bf16*)big;                       // [8192][256]
  bf16*  ff1  = (bf16*)big;                       // [8192][1024]
  bf16*  qp   = (bf16*)pkbuf;                     // 4 MB
  bf16*  kp   = (bf16*)(pkbuf + (size_t)4*1024*1024);
  bf16*  vt   = (bf16*)(pkbuf + (size_t)8*1024*1024);
  float* yf   = (float*)pkbuf;                    // 8 MB (qp/kp dead when live)

  prep_t<<<dim3(32,32,26), dim3(32,8), 0, stream>>>(Wq,Wk,Wv,Wo,W1,W2,Wc,bq,bk,bv,
                                                    WqkvT,WoT,W1T,W2T,WcT,bqkv);
  embed_kernel<<<dim3(M_), 256, 0, stream>>>(ids, emb, x);

  for (int l = 0; l < L_; ++l) {
    gemm_qkv<<<dim3(64,12), 256, 0, stream>>>(
        x, WqkvT + (size_t)l*768*256, bqkv + l*768, qp, kp, vt);
    attn_kernel<<<dim3(16,8,8), 256, 0, stream>>>(qp, kp, vt, tsl, aout);
    gemm_bt64<false,false,false><<<dim3(128,4), 256, 0, stream>>>(
        aout, WoT + (size_t)l*65536, bo + l*256, yf, M_, 256, 256);
    addln_kernel<<<dim3(2048), 256, 0, stream>>>(x, yf, g1 + l*256, be1 + l*256, x);
    gemm_bt<true,true><<<dim3(64,16), 256, 0, stream>>>(
        x, W1T + (size_t)l*262144, b1 + l*1024, ff1, M_, 1024, 256);
    gemm_bt64<false,false,false><<<dim3(128,4), 256, 0, stream>>>(
        ff1, W2T + (size_t)l*262144, b2 + l*256, yf, M_, 256, 1024);
    addln_kernel<<<dim3(2048), 256, 0, stream>>>(x, yf, g2 + l*256, be2 + l*256, x);
  }

  gemm_bt64<false,false,true><<<dim3(128,2), 256, 0, stream>>>(
      x, WcT, bc, (float*)d_out, M_, V_, 256);
}

// Round 7
// 481.898 us; speedup vs baseline: 1.2807x; 1.0079x over previous
//
#include <hip/hip_runtime.h>
#include <hip/hip_bf16.h>
#include <stdint.h>

#define B_   8
#define S_   1024
#define D_   256
#define H_   8
#define DH_  32
#define L_   4
#define V_   100
#define DFF_ 1024
#define M_   (B_*S_)   // 8192

using bf16 = __hip_bfloat16;
typedef __bf16 bf16x8 __attribute__((ext_vector_type(8)));
typedef float  f32x4  __attribute__((ext_vector_type(4)));

static __device__ __forceinline__ float b2f(unsigned short u) {
  union { unsigned int i; float f; } w; w.i = ((unsigned int)u) << 16; return w.f;
}

// async global->LDS DMA: 16B/lane, LDS dest = wave-uniform base + lane*16
static __device__ __forceinline__ void load_lds16(const void* g, void* l) {
  __builtin_amdgcn_global_load_lds((const __attribute__((address_space(1))) void*)g,
                                   (__attribute__((address_space(3))) void*)l,
                                   16, 0, 0);
}

// DPP cross-lane reductions over the 16-lane l15 group (== DPP row).
template<int CTRL>
static __device__ __forceinline__ float dppf(float v) {
  union { float f; int i; } a, r;
  a.f = v;
  r.i = __builtin_amdgcn_update_dpp(0, a.i, CTRL, 0xF, 0xF, true);
  return r.f;
}
static __device__ __forceinline__ float red_max16(float v) {
  v = fmaxf(v, dppf<0xB1>(v));    // quad_perm [1,0,3,2]
  v = fmaxf(v, dppf<0x4E>(v));    // quad_perm [2,3,0,1]
  v = fmaxf(v, dppf<0x141>(v));   // row_half_mirror
  v = fmaxf(v, dppf<0x140>(v));   // row_mirror
  return v;
}
static __device__ __forceinline__ float red_sum16(float v) {
  v += dppf<0xB1>(v);
  v += dppf<0x4E>(v);
  v += dppf<0x141>(v);
  v += dppf<0x140>(v);
  return v;
}

// ---------------------------------------------------------------------------
// Tiled weight prep: f32 [R][C] -> bf16 [C][R], 32x32 LDS tiles, coalesced.
// ---------------------------------------------------------------------------
__global__ void prep_t(const float* __restrict__ Wq, const float* __restrict__ Wk,
                       const float* __restrict__ Wv, const float* __restrict__ Wo,
                       const float* __restrict__ W1, const float* __restrict__ W2,
                       const float* __restrict__ Wc,
                       const float* __restrict__ bq, const float* __restrict__ bk,
                       const float* __restrict__ bv,
                       bf16* __restrict__ WqkvT, bf16* __restrict__ WoT,
                       bf16* __restrict__ W1T, bf16* __restrict__ W2T,
                       bf16* __restrict__ WcT, float* __restrict__ bqkv)
{
  const int z = blockIdx.z;
  if (z == 25) {                                 // fused qkv bias
    if (blockIdx.x || blockIdx.y) return;
    const int tid = threadIdx.y*32 + threadIdx.x;
    for (int i = tid; i < L_*768; i += 256) {
      const int l2 = i / 768, j = i % 768;
      const float* src = (j < 256) ? bq : (j < 512) ? bk : bv;
      bqkv[i] = src[l2*256 + (j & 255)];
    }
    return;
  }
  const float* src; bf16* dst; int R, C, Cd;
  if (z < 12) {
    const int l = z / 3, w = z % 3;
    src = ((w == 0) ? Wq : (w == 1) ? Wk : Wv) + (size_t)l*65536;
    R = 256; C = 256; Cd = 256;
    dst = WqkvT + (size_t)l*196608 + (size_t)w*65536;
  } else if (z < 16) {
    const int l = z - 12;
    src = Wo + (size_t)l*65536; R = 256; C = 256; Cd = 256;
    dst = WoT + (size_t)l*65536;
  } else if (z < 20) {
    const int l = z - 16;
    src = W1 + (size_t)l*262144; R = 256; C = 1024; Cd = 1024;
    dst = W1T + (size_t)l*262144;
  } else if (z < 24) {
    const int l = z - 20;
    src = W2 + (size_t)l*262144; R = 1024; C = 256; Cd = 256;
    dst = W2T + (size_t)l*262144;
  } else {
    src = Wc; R = 256; C = 100; Cd = 128;
    dst = WcT;
  }
  const int c0 = blockIdx.x*32, r0 = blockIdx.y*32;
  if (c0 >= Cd || r0 >= R) return;
  __shared__ float t[32][33];
  #pragma unroll
  for (int i = 0; i < 4; ++i) {
    const int r = r0 + threadIdx.y + i*8;
    const int c = c0 + threadIdx.x;
    t[threadIdx.y + i*8][threadIdx.x] = (r < R && c < C) ? src[(size_t)r*C + c] : 0.f;
  }
  __syncthreads();
  #pragma unroll
  for (int i = 0; i < 4; ++i) {
    const int c = c0 + threadIdx.y + i*8;
    const int r = r0 + threadIdx.x;
    if (c < Cd && r < R)
      dst[(size_t)c*R + r] = (bf16)t[threadIdx.x][threadIdx.y + i*8];
  }
}

// ---------------------------------------------------------------------------
__global__ void embed_kernel(const int* __restrict__ ids, const float* __restrict__ emb,
                             bf16* __restrict__ x)
{
  const int bs = blockIdx.x;
  const int d  = threadIdx.x;
  const int s  = bs & (S_-1);
  const int id = ids[bs];
  const int f  = (d < 128) ? (2*d) : (2*(d-128)+1);
  const float inv = powf(10000.f, -(float)f * (1.f/256.f));
  const float pe  = sinf((float)s * inv);
  x[(size_t)bs*D_ + d] = (bf16)(emb[(size_t)id*D_ + d] + pe);
}

// ---------------------------------------------------------------------------
// QKV GEMM with packed epilogue -> qp[bh][s][32], kp[bh][s][32], vt[bh][d][s].
// 128x64 tile, BK=32, grid (64,12).
// ---------------------------------------------------------------------------
__global__ __launch_bounds__(256) void gemm_qkv(
    const bf16* __restrict__ A, const bf16* __restrict__ BT,
    const float* __restrict__ bias,
    bf16* __restrict__ qp, bf16* __restrict__ kp, bf16* __restrict__ vt)
{
  __shared__ bf16 As[128*32];
  __shared__ bf16 Bs[64*32];
  __shared__ bf16 Vs[64][136];
  const int tid  = threadIdx.x;
  const int lane = tid & 63, wave = tid >> 6;
  const int quad = lane >> 4, l15 = lane & 15;
  const int m0 = blockIdx.x * 128;
  const int n0 = blockIdx.y * 64;
  const int wm = (wave & 1) * 64;
  const int wn = (wave >> 1) * 32;
  const int K = 256;

  const bf16* a0 = A  + (size_t)m0 * K;
  const bf16* b0 = BT + (size_t)n0 * K;
  const int row = tid >> 2;
  const int ch  = (tid & 3) * 8;

  f32x4 acc[4][2] = {};

  for (int k0 = 0; k0 < K; k0 += 32) {
    __syncthreads();
    load_lds16(a0 + (size_t)row*K      + k0 + ch, (char*)As + (size_t)wave*1024);
    load_lds16(a0 + (size_t)(row+64)*K + k0 + ch, (char*)As + 4096 + (size_t)wave*1024);
    load_lds16(b0 + (size_t)row*K      + k0 + ch, (char*)Bs + (size_t)wave*1024);
    __syncthreads();
    bf16x8 af[4], bfr[2];
    #pragma unroll
    for (int mt = 0; mt < 4; ++mt)
      af[mt] = *(const bf16x8*)(As + (wm + mt*16 + l15)*32 + quad*8);
    #pragma unroll
    for (int nt = 0; nt < 2; ++nt)
      bfr[nt] = *(const bf16x8*)(Bs + (wn + nt*16 + l15)*32 + quad*8);
    #pragma unroll
    for (int mt = 0; mt < 4; ++mt)
      #pragma unroll
      for (int nt = 0; nt < 2; ++nt)
        acc[mt][nt] = __builtin_amdgcn_mfma_f32_16x16x32_bf16(af[mt], bfr[nt], acc[mt][nt], 0, 0, 0);
  }

  const int seg = n0 >> 8;            // 0=Q, 1=K, 2=V
  const int b  = m0 >> 10;
  const int s0 = m0 & 1023;

  if (seg < 2) {
    bf16* dst = seg ? kp : qp;
    #pragma unroll
    for (int nt = 0; nt < 2; ++nt) {
      const int n  = n0 + wn + nt*16 + l15;
      const int nn = n & 255;
      const int h = nn >> 5, d = nn & 31;
      const float bvs = bias[n];
      bf16* hb = dst + (((size_t)b*H_ + h)*S_)*DH_ + d;
      #pragma unroll
      for (int mt = 0; mt < 4; ++mt) {
        const int ml = wm + mt*16 + quad*4;
        #pragma unroll
        for (int r = 0; r < 4; ++r)
          hb[(size_t)(s0 + ml + r)*DH_] = (bf16)(acc[mt][nt][r] + bvs);
      }
    }
  } else {
    #pragma unroll
    for (int nt = 0; nt < 2; ++nt) {
      const int nl = wn + nt*16 + l15;
      const float bvs = bias[n0 + nl];
      #pragma unroll
      for (int mt = 0; mt < 4; ++mt) {
        const int ml = wm + mt*16 + quad*4;
        #pragma unroll
        for (int r = 0; r < 4; ++r)
          Vs[nl][ml + r] = (bf16)(acc[mt][nt][r] + bvs);
      }
    }
    __syncthreads();
    #pragma unroll
    for (int t = 0; t < 2; ++t) {
      const int vrow = (tid >> 3) + 32*t;
      const int soff = (tid & 7) * 16;
      const int nn = (n0 + vrow) & 255;
      const int h = nn >> 5, d = nn & 31;
      bf16* dst = vt + (((size_t)b*H_ + h)*DH_ + d)*S_ + s0 + soff;
      *(bf16x8*)dst       = *(const bf16x8*)&Vs[vrow][soff];
      *(bf16x8*)(dst + 8) = *(const bf16x8*)&Vs[vrow][soff + 8];
    }
  }
}

// ---------------------------------------------------------------------------
// Generic GEMM 128x64 tile (bias + optional relu) — used for FF1.
// ---------------------------------------------------------------------------
template<bool RELU, bool OUT_BF16>
__global__ __launch_bounds__(256) void gemm_bt(
    const bf16* __restrict__ A, const bf16* __restrict__ BT,
    const float* __restrict__ bias, void* __restrict__ C,
    int M, int N, int K)
{
  __shared__ bf16 As[128*32];
  __shared__ bf16 Bs[64*32];
  const int tid  = threadIdx.x;
  const int lane = tid & 63, wave = tid >> 6;
  const int quad = lane >> 4, l15 = lane & 15;
  const int m0 = blockIdx.x * 128;
  const int n0 = blockIdx.y * 64;
  const int wm = (wave & 1) * 64;
  const int wn = (wave >> 1) * 32;

  const bf16* a0 = A  + (size_t)m0 * K;
  const bf16* b0 = BT + (size_t)n0 * K;
  const int row = tid >> 2;
  const int ch  = (tid & 3) * 8;

  f32x4 acc[4][2] = {};

  for (int k0 = 0; k0 < K; k0 += 32) {
    __syncthreads();
    load_lds16(a0 + (size_t)row*K      + k0 + ch, (char*)As + (size_t)wave*1024);
    load_lds16(a0 + (size_t)(row+64)*K + k0 + ch, (char*)As + 4096 + (size_t)wave*1024);
    load_lds16(b0 + (size_t)row*K      + k0 + ch, (char*)Bs + (size_t)wave*1024);
    __syncthreads();
    bf16x8 af[4], bfr[2];
    #pragma unroll
    for (int mt = 0; mt < 4; ++mt)
      af[mt] = *(const bf16x8*)(As + (wm + mt*16 + l15)*32 + quad*8);
    #pragma unroll
    for (int nt = 0; nt < 2; ++nt)
      bfr[nt] = *(const bf16x8*)(Bs + (wn + nt*16 + l15)*32 + quad*8);
    #pragma unroll
    for (int mt = 0; mt < 4; ++mt)
      #pragma unroll
      for (int nt = 0; nt < 2; ++nt)
        acc[mt][nt] = __builtin_amdgcn_mfma_f32_16x16x32_bf16(af[mt], bfr[nt], acc[mt][nt], 0, 0, 0);
  }

  #pragma unroll
  for (int nt = 0; nt < 2; ++nt) {
    const int n = n0 + wn + nt*16 + l15;
    const float bvs = bias[n];
    #pragma unroll
    for (int mt = 0; mt < 4; ++mt) {
      const int mr = m0 + wm + mt*16 + quad*4;
      #pragma unroll
      for (int r = 0; r < 4; ++r) {
        float v = acc[mt][nt][r] + bvs;
        if (RELU) v = fmaxf(v, 0.f);
        if (OUT_BF16) ((bf16*)C)[(size_t)(mr + r)*N + n] = (bf16)v;
        else          ((float*)C)[(size_t)(mr + r)*N + n] = v;
      }
    }
  }
}

// ---------------------------------------------------------------------------
// GEMM 64x64 tile — classifier (NMASK).
// ---------------------------------------------------------------------------
template<bool RELU, bool OUT_BF16, bool NMASK>
__global__ __launch_bounds__(256) void gemm_bt64(
    const bf16* __restrict__ A, const bf16* __restrict__ BT,
    const float* __restrict__ bias, void* __restrict__ C,
    int M, int N, int K)
{
  __shared__ bf16 As[64*32];
  __shared__ bf16 Bs[64*32];
  const int tid  = threadIdx.x;
  const int lane = tid & 63, wave = tid >> 6;
  const int quad = lane >> 4, l15 = lane & 15;
  const int m0 = blockIdx.x * 64;
  const int n0 = blockIdx.y * 64;
  const int wm = (wave & 1) * 32;
  const int wn = (wave >> 1) * 32;

  const bf16* a0 = A  + (size_t)m0 * K;
  const bf16* b0 = BT + (size_t)n0 * K;
  const int row = tid >> 2;
  const int ch  = (tid & 3) * 8;

  f32x4 acc[2][2] = {};

  for (int k0 = 0; k0 < K; k0 += 32) {
    __syncthreads();
    load_lds16(a0 + (size_t)row*K + k0 + ch, (char*)As + (size_t)wave*1024);
    load_lds16(b0 + (size_t)row*K + k0 + ch, (char*)Bs + (size_t)wave*1024);
    __syncthreads();
    bf16x8 af[2], bfr[2];
    #pragma unroll
    for (int mt = 0; mt < 2; ++mt)
      af[mt] = *(const bf16x8*)(As + (wm + mt*16 + l15)*32 + quad*8);
    #pragma unroll
    for (int nt = 0; nt < 2; ++nt)
      bfr[nt] = *(const bf16x8*)(Bs + (wn + nt*16 + l15)*32 + quad*8);
    #pragma unroll
    for (int mt = 0; mt < 2; ++mt)
      #pragma unroll
      for (int nt = 0; nt < 2; ++nt)
        acc[mt][nt] = __builtin_amdgcn_mfma_f32_16x16x32_bf16(af[mt], bfr[nt], acc[mt][nt], 0, 0, 0);
  }

  #pragma unroll
  for (int nt = 0; nt < 2; ++nt) {
    const int n = n0 + wn + nt*16 + l15;
    if (NMASK && n >= N) continue;
    const float bvs = bias[n];
    #pragma unroll
    for (int mt = 0; mt < 2; ++mt) {
      const int mr = m0 + wm + mt*16 + quad*4;
      #pragma unroll
      for (int r = 0; r < 4; ++r) {
        float v = acc[mt][nt][r] + bvs;
        if (RELU) v = fmaxf(v, 0.f);
        if (OUT_BF16) ((bf16*)C)[(size_t)(mr + r)*N + n] = (bf16)v;
        else          ((float*)C)[(size_t)(mr + r)*N + n] = v;
      }
    }
  }
}

// ---------------------------------------------------------------------------
// Fused GEMM + residual + LayerNorm:  x = LN(x + A@BT^T + bias)*g + be.
// M-tile 16, N=256 (full row in-block), runtime K. grid (M/16), block 256.
// Wave w owns cols [64w, 64w+64); acc[4] per wave. LN stats: per-row DPP
// partial + cross-wave LDS combine. x in/out may alias (rows are private).
// ---------------------------------------------------------------------------
__global__ __launch_bounds__(256) void gemm_ln(
    const bf16* __restrict__ A, const bf16* __restrict__ BT,
    const float* __restrict__ bias, const float* __restrict__ g,
    const float* __restrict__ be, bf16* xio, int K)
{
  __shared__ bf16 As[16*32];        // 1 KB
  __shared__ bf16 Bs[256*32];       // 16 KB
  __shared__ bf16 Xs[16][264];      // 8.25 KB
  __shared__ float sums[4][16][2];  // per-wave row partials

  const int tid  = threadIdx.x;
  const int lane = tid & 63, wave = tid >> 6;
  const int quad = lane >> 4, l15 = lane & 15;
  const int m0 = blockIdx.x * 16;
  const int wn = wave * 64;

  const bf16* a0 = A + (size_t)m0 * K;
  const int ch = (tid & 3) * 8;

  f32x4 acc[4] = {};

  for (int k0 = 0; k0 < K; k0 += 32) {
    __syncthreads();
    if (wave == 0)
      load_lds16(a0 + (size_t)(lane >> 2)*K + k0 + (lane & 3)*8, (char*)As);
    #pragma unroll
    for (int j = 0; j < 4; ++j)
      load_lds16(BT + (size_t)(64*j + (tid >> 2))*K + k0 + ch,
                 (char*)Bs + j*4096 + (size_t)wave*1024);
    __syncthreads();
    const bf16x8 af = *(const bf16x8*)(As + l15*32 + quad*8);
    #pragma unroll
    for (int nt = 0; nt < 4; ++nt) {
      const bf16x8 bfr = *(const bf16x8*)(Bs + (wn + nt*16 + l15)*32 + quad*8);
      acc[nt] = __builtin_amdgcn_mfma_f32_16x16x32_bf16(af, bfr, acc[nt], 0, 0, 0);
    }
  }

  // stage x tile (16 rows x 256 cols) coalesced into Xs
  {
    const int xr = tid >> 4, xc = (tid & 15) * 16;
    const bf16* src = xio + (size_t)(m0 + xr)*D_ + xc;
    *(bf16x8*)&Xs[xr][xc]     = *(const bf16x8*)src;
    *(bf16x8*)&Xs[xr][xc + 8] = *(const bf16x8*)(src + 8);
  }
  __syncthreads();

  // v = x + y; per-row partial stats via DPP over the l15 group
  float v[4][4];   // [r][nt]
  float bvs[4];
  #pragma unroll
  for (int nt = 0; nt < 4; ++nt) bvs[nt] = bias[wn + nt*16 + l15];
  #pragma unroll
  for (int r = 0; r < 4; ++r) {
    const int rr = quad*4 + r;
    float ls = 0.f, lq = 0.f;
    #pragma unroll
    for (int nt = 0; nt < 4; ++nt) {
      const float y = acc[nt][r] + bvs[nt];
      const float xv = b2f(*(const unsigned short*)&Xs[rr][wn + nt*16 + l15]);
      const float vv = xv + y;
      v[r][nt] = vv;
      ls += vv;
      lq += vv*vv;
    }
    ls = red_sum16(ls);
    lq = red_sum16(lq);
    if (l15 == 0) { sums[wave][rr][0] = ls; sums[wave][rr][1] = lq; }
  }
  __syncthreads();

  float gv[4], bev[4];
  #pragma unroll
  for (int nt = 0; nt < 4; ++nt) {
    gv[nt]  = g[wn + nt*16 + l15];
    bev[nt] = be[wn + nt*16 + l15];
  }
  #pragma unroll
  for (int r = 0; r < 4; ++r) {
    const int rr = quad*4 + r;
    const float ts = sums[0][rr][0] + sums[1][rr][0] + sums[2][rr][0] + sums[3][rr][0];
    const float tq = sums[0][rr][1] + sums[1][rr][1] + sums[2][rr][1] + sums[3][rr][1];
    const float mean = ts * (1.f/256.f);
    const float var  = tq * (1.f/256.f) - mean*mean;
    const float inv  = rsqrtf(var + 1e-5f);
    #pragma unroll
    for (int nt = 0; nt < 4; ++nt) {
      const bf16 o = (bf16)((v[r][nt] - mean)*inv*gv[nt] + bev[nt]);
      Xs[rr][wn + nt*16 + l15] = o;
    }
  }
  __syncthreads();

  // coalesced store back
  {
    const int xr = tid >> 4, xc = (tid & 15) * 16;
    bf16* dst = xio + (size_t)(m0 + xr)*D_ + xc;
    *(bf16x8*)dst       = *(const bf16x8*)&Xs[xr][xc];
    *(bf16x8*)(dst + 8) = *(const bf16x8*)&Xs[xr][xc + 8];
  }
}

// ---------------------------------------------------------------------------
// Flash attention, causal — unchanged from round 6 (verified).
// ---------------------------------------------------------------------------
__global__ __launch_bounds__(256) void attn_kernel(
    const bf16* __restrict__ qp, const bf16* __restrict__ kp,
    const bf16* __restrict__ vt, const int* __restrict__ tsl,
    bf16* __restrict__ out)
{
  const int h = blockIdx.y, b = blockIdx.z;
  const int lane = threadIdx.x & 63, wave = threadIdx.x >> 6;
  const int quad = lane >> 4, l15 = lane & 15;
  const int sid = blockIdx.x + wave*16;
  const int q0 = sid*16;
  const int len = tsl[b];

  __shared__ bf16 Pl[4][16*64];

  const size_t bh = (size_t)b*H_ + h;
  const bf16* qb = qp + bh*S_*DH_;
  const bf16* kb = kp + bh*S_*DH_;
  const bf16* vb = vt + bh*DH_*S_;

  const bf16x8 qf = *(const bf16x8*)(qb + (size_t)(q0 + l15)*DH_ + quad*8);

  const float NEG = -1e30f;
  float m_run[4], l_run[4], al[4];
  f32x4 o0 = {0.f,0.f,0.f,0.f}, o1 = {0.f,0.f,0.f,0.f};
  #pragma unroll
  for (int r = 0; r < 4; ++r) { m_run[r] = NEG; l_run[r] = 0.f; }

  const float scale = 0.17677669529663687f;
  bf16* pw = &Pl[wave][0];
  const int qrow0 = q0 + quad*4;

  if (len >= S_) {
    const int dt = sid >> 2;
    for (int ks = 0; ks <= dt; ++ks) {
      const int k0 = ks*64;
      f32x4 s[4];
      #pragma unroll
      for (int nt = 0; nt < 4; ++nt) {
        const bf16x8 kf = *(const bf16x8*)(kb + (size_t)(k0 + nt*16 + l15)*DH_ + quad*8);
        const f32x4 z = {0.f,0.f,0.f,0.f};
        s[nt] = __builtin_amdgcn_mfma_f32_16x16x32_bf16(qf, kf, z, 0, 0, 0);
      }
      float mx[4];
      if (ks == dt) {
        #pragma unroll
        for (int r = 0; r < 4; ++r) mx[r] = NEG;
        #pragma unroll
        for (int nt = 0; nt < 4; ++nt) {
          const int kpos = k0 + nt*16 + l15;
          #pragma unroll
          for (int r = 0; r < 4; ++r) {
            const float v = (kpos <= qrow0 + r) ? s[nt][r] * scale : NEG;
            s[nt][r] = v;
            mx[r] = fmaxf(mx[r], v);
          }
        }
      } else {
        #pragma unroll
        for (int r = 0; r < 4; ++r) {
          float v0 = s[0][r] * scale; s[0][r] = v0;
          float v1 = s[1][r] * scale; s[1][r] = v1;
          float v2 = s[2][r] * scale; s[2][r] = v2;
          float v3 = s[3][r] * scale; s[3][r] = v3;
          mx[r] = fmaxf(fmaxf(v0, v1), fmaxf(v2, v3));
        }
      }
      #pragma unroll
      for (int r = 0; r < 4; ++r) {
        const float mn = fmaxf(m_run[r], red_max16(mx[r]));
        al[r] = __expf(m_run[r] - mn);
        m_run[r] = mn;
      }
      float ls[4];
      #pragma unroll
      for (int r = 0; r < 4; ++r) {
        float p0 = __expf(s[0][r] - m_run[r]); s[0][r] = p0;
        float p1 = __expf(s[1][r] - m_run[r]); s[1][r] = p1;
        float p2 = __expf(s[2][r] - m_run[r]); s[2][r] = p2;
        float p3 = __expf(s[3][r] - m_run[r]); s[3][r] = p3;
        ls[r] = (p0 + p1) + (p2 + p3);
      }
      #pragma unroll
      for (int r = 0; r < 4; ++r) {
        l_run[r] = l_run[r]*al[r] + red_sum16(ls[r]);
        o0[r] *= al[r];
        o1[r] *= al[r];
      }
      #pragma unroll
      for (int nt = 0; nt < 4; ++nt)
        #pragma unroll
        for (int r = 0; r < 4; ++r)
          pw[(quad*4+r)*64 + nt*16 + l15] = (bf16)s[nt][r];
      asm volatile("s_waitcnt lgkmcnt(0)" ::: "memory");
      #pragma unroll
      for (int kc = 0; kc < 2; ++kc) {
        const bf16x8 pf = *(const bf16x8*)(pw + l15*64 + kc*32 + quad*8);
        const bf16x8 vf0 = *(const bf16x8*)(vb + (size_t)l15*S_ + k0 + kc*32 + quad*8);
        o0 = __builtin_amdgcn_mfma_f32_16x16x32_bf16(pf, vf0, o0, 0, 0, 0);
        const bf16x8 vf1 = *(const bf16x8*)(vb + (size_t)(16 + l15)*S_ + k0 + kc*32 + quad*8);
        o1 = __builtin_amdgcn_mfma_f32_16x16x32_bf16(pf, vf1, o1, 0, 0, 0);
      }
    }
  } else {
    const int nk = (sid >> 2) + 1;
    for (int ks = 0; ks < nk; ++ks) {
      const int k0 = ks*64;
      f32x4 s[4];
      #pragma unroll
      for (int nt = 0; nt < 4; ++nt) {
        const bf16x8 kf = *(const bf16x8*)(kb + (size_t)(k0 + nt*16 + l15)*DH_ + quad*8);
        const f32x4 z = {0.f,0.f,0.f,0.f};
        s[nt] = __builtin_amdgcn_mfma_f32_16x16x32_bf16(qf, kf, z, 0, 0, 0);
      }
      float mx[4];
      #pragma unroll
      for (int r = 0; r < 4; ++r) mx[r] = NEG;
      #pragma unroll
      for (int nt = 0; nt < 4; ++nt) {
        const int kpos = k0 + nt*16 + l15;
        #pragma unroll
        for (int r = 0; r < 4; ++r) {
          const int qr = qrow0 + r;
          const bool ok = (kpos <= qr) && (kpos < len) && (qr < len);
          const float v = ok ? s[nt][r] * scale : NEG;
          s[nt][r] = v;
          mx[r] = fmaxf(mx[r], v);
        }
      }
      #pragma unroll
      for (int r = 0; r < 4; ++r) {
        const float mn = fmaxf(m_run[r], red_max16(mx[r]));
        al[r] = (m_run[r] > -1e29f) ? __expf(m_run[r] - mn) : 0.f;
        m_run[r] = mn;
      }
      float ls[4] = {0.f,0.f,0.f,0.f};
      #pragma unroll
      for (int nt = 0; nt < 4; ++nt)
        #pragma unroll
        for (int r = 0; r < 4; ++r) {
          const float vv = s[nt][r];
          const float p = (vv > -1e29f && m_run[r] > -1e29f) ? __expf(vv - m_run[r]) : 0.f;
          s[nt][r] = p;
          ls[r] += p;
        }
      #pragma unroll
      for (int r = 0; r < 4; ++r) {
        l_run[r] = l_run[r]*al[r] + red_sum16(ls[r]);
        o0[r] *= al[r];
        o1[r] *= al[r];
      }
      #pragma unroll
      for (int nt = 0; nt < 4; ++nt)
        #pragma unroll
        for (int r = 0; r < 4; ++r)
          pw[(quad*4+r)*64 + nt*16 + l15] = (bf16)s[nt][r];
      asm volatile("s_waitcnt lgkmcnt(0)" ::: "memory");
      #pragma unroll
      for (int kc = 0; kc < 2; ++kc) {
        const bf16x8 pf = *(const bf16x8*)(pw + l15*64 + kc*32 + quad*8);
        const bf16x8 vf0 = *(const bf16x8*)(vb + (size_t)l15*S_ + k0 + kc*32 + quad*8);
        o0 = __builtin_amdgcn_mfma_f32_16x16x32_bf16(pf, vf0, o0, 0, 0, 0);
        const bf16x8 vf1 = *(const bf16x8*)(vb + (size_t)(16 + l15)*S_ + k0 + kc*32 + quad*8);
        o1 = __builtin_amdgcn_mfma_f32_16x16x32_bf16(pf, vf1, o1, 0, 0, 0);
      }
    }
  }

  bf16* ob = out + (size_t)b*S_*D_ + h*DH_;
  #pragma unroll
  for (int r = 0; r < 4; ++r) {
    const float inv = 1.f / fmaxf(l_run[r], 1e-30f);
    const size_t rowoff = (size_t)(q0 + quad*4 + r)*D_;
    ob[rowoff + l15]      = (bf16)(o0[r]*inv);
    ob[rowoff + 16 + l15] = (bf16)(o1[r]*inv);
  }
}

// ---------------------------------------------------------------------------
extern "C" void kernel_launch(void* const* d_in, const int* in_sizes, int n_in,
                              void* d_out, int out_size, void* d_ws, size_t ws_size,
                              hipStream_t stream)
{
  const int*   ids = (const int*)d_in[0];
  const int*   tsl = (const int*)d_in[1];
  const float* emb = (const float*)d_in[2];
  const float* Wq  = (const float*)d_in[3];
  const float* bq  = (const float*)d_in[4];
  const float* Wk  = (const float*)d_in[5];
  const float* bk  = (const float*)d_in[6];
  const float* Wv  = (const float*)d_in[7];
  const float* bv  = (const float*)d_in[8];
  const float* Wo  = (const float*)d_in[9];
  const float* bo  = (const float*)d_in[10];
  const float* W1  = (const float*)d_in[11];
  const float* b1  = (const float*)d_in[12];
  const float* W2  = (const float*)d_in[13];
  const float* b2  = (const float*)d_in[14];
  const float* g1  = (const float*)d_in[15];
  const float* be1 = (const float*)d_in[16];
  const float* g2  = (const float*)d_in[17];
  const float* be2 = (const float*)d_in[18];
  const float* Wc  = (const float*)d_in[19];
  const float* bc  = (const float*)d_in[20];

  if (ws_size < (size_t)40*1024*1024) return;

  char* p = (char*)d_ws;
  auto carve = [&](size_t bytes) { void* r = (void*)p; p += (bytes + 255) & ~(size_t)255; return r; };
  bf16*  x     = (bf16*) carve((size_t)M_*D_*2);        // 4 MB, persistent
  char*  big   = (char*) carve((size_t)M_*DFF_*2);      // 16 MB: aout | ff1
  char*  pkbuf = (char*) carve((size_t)12*1024*1024);   // 12 MB: qp, kp, vt
  bf16*  WqkvT = (bf16*) carve((size_t)L_*768*256*2);
  bf16*  WoT   = (bf16*) carve((size_t)L_*65536*2);
  bf16*  W1T   = (bf16*) carve((size_t)L_*262144*2);
  bf16*  W2T   = (bf16*) carve((size_t)L_*262144*2);
  bf16*  WcT   = (bf16*) carve((size_t)128*256*2);
  float* bqkv  = (float*)carve((size_t)L_*768*4);

  bf16*  aout = (bf16*)big;                       // [8192][256]
  bf16*  ff1  = (bf16*)big;                       // [8192][1024] (aout dead)
  bf16*  qp   = (bf16*)pkbuf;
  bf16*  kp   = (bf16*)(pkbuf + (size_t)4*1024*1024);
  bf16*  vt   = (bf16*)(pkbuf + (size_t)8*1024*1024);

  prep_t<<<dim3(32,32,26), dim3(32,8), 0, stream>>>(Wq,Wk,Wv,Wo,W1,W2,Wc,bq,bk,bv,
                                                    WqkvT,WoT,W1T,W2T,WcT,bqkv);
  embed_kernel<<<dim3(M_), 256, 0, stream>>>(ids, emb, x);

  for (int l = 0; l < L_; ++l) {
    gemm_qkv<<<dim3(64,12), 256, 0, stream>>>(
        x, WqkvT + (size_t)l*768*256, bqkv + l*768, qp, kp, vt);
    attn_kernel<<<dim3(16,8,8), 256, 0, stream>>>(qp, kp, vt, tsl, aout);
    gemm_ln<<<dim3(512), 256, 0, stream>>>(
        aout, WoT + (size_t)l*65536, bo + l*256, g1 + l*256, be1 + l*256, x, 256);
    gemm_bt<true,true><<<dim3(64,16), 256, 0, stream>>>(
        x, W1T + (size_t)l*262144, b1 + l*1024, ff1, M_, 1024, 256);
    gemm_ln<<<dim3(512), 256, 0, stream>>>(
        ff1, W2T + (size_t)l*262144, b2 + l*256, g2 + l*256, be2 + l*256, x, 1024);
  }

  gemm_bt64<false,false,true><<<dim3(128,2), 256, 0, stream>>>(
      x, WcT, bc, (float*)d_out, M_, V_, 256);
}